// Round 2
// baseline (594.298 us; speedup 1.0000x reference)
//
#include <hip/hip_runtime.h>
#include <hip/hip_bf16.h>
#include <stdint.h>

// ---------------------------------------------------------------------------
// HyenaBaseBlock: LN -> FFT causal conv (n=8192) -> +z -> LN -> *FFN(x) -> LN
// -> FFN -> +residual.  f32 FFT in LDS, bf16 MFMA GEMMs for the FFNs.
// ---------------------------------------------------------------------------

typedef __attribute__((ext_vector_type(8))) short bf16x8;
typedef __attribute__((ext_vector_type(4))) float f32x4;
typedef const __attribute__((address_space(1))) void* as1cv;
typedef __attribute__((address_space(3))) void* as3v;

#define DEVI __device__ __forceinline__

#define B_ 4
#define L_ 4096
#define D_ 512
#define MSEQ 16384   // B_*L_

DEVI void gld_lds16(const void* g, void* l) {
  __builtin_amdgcn_global_load_lds((as1cv)(uintptr_t)g, (as3v)(uintptr_t)l, 16, 0, 0);
}

DEVI unsigned short to_bf16_bits(float v) {
  __hip_bfloat16 h = __float2bfloat16(v);
  return *reinterpret_cast<unsigned short*>(&h);
}

// ---------------- pos FFN layer 1: p1 = silu(pos @ w1^T + b1)  [4096,256] ---
__global__ __launch_bounds__(256) void k_posffn1(const float* __restrict__ pos,
                                                 const float* __restrict__ w1,
                                                 const float* __restrict__ b1,
                                                 float* __restrict__ p1) {
  __shared__ float sp[16 * 128];
  const int tid = threadIdx.x;
  const int m0 = blockIdx.x * 16;
  const float4* src = (const float4*)(pos + (size_t)m0 * 128);
  float4* dst = (float4*)sp;
  for (int i = tid; i < 512; i += 256) dst[i] = src[i];
  __syncthreads();
  const int n = tid;
  float acc[16];
  const float bias = b1[n];
#pragma unroll
  for (int m = 0; m < 16; ++m) acc[m] = bias;
  const float* w = w1 + (size_t)n * 128;
  for (int k = 0; k < 128; ++k) {
    const float wv = w[k];
#pragma unroll
    for (int m = 0; m < 16; ++m) acc[m] = fmaf(sp[m * 128 + k], wv, acc[m]);
  }
#pragma unroll
  for (int m = 0; m < 16; ++m) {
    const float v = acc[m];
    p1[(size_t)(m0 + m) * 256 + n] = v / (1.f + __expf(-v));
  }
}

// ---- pos FFN layer 2 + window, write transposed whT[d][t] = win[t]*h[t][d] -
__global__ __launch_bounds__(256) void k_posffn2(const float* __restrict__ p1,
                                                 const float* __restrict__ w2,
                                                 const float* __restrict__ b2,
                                                 const float* __restrict__ a,
                                                 float* __restrict__ whT) {
  __shared__ float sp[16 * 256];
  __shared__ float so[16 * 512];
  const int tid = threadIdx.x;
  const int t0 = blockIdx.x * 16;
  const float4* src = (const float4*)(p1 + (size_t)t0 * 256);
  float4* dst = (float4*)sp;
  for (int i = tid; i < 1024; i += 256) dst[i] = src[i];
  __syncthreads();
  for (int half = 0; half < 2; ++half) {
    const int d = tid + half * 256;
    float acc[16];
    const float bias = b2[d];
#pragma unroll
    for (int m = 0; m < 16; ++m) acc[m] = bias;
    const float* w = w2 + (size_t)d * 256;
    for (int k = 0; k < 256; ++k) {
      const float wv = w[k];
#pragma unroll
      for (int m = 0; m < 16; ++m) acc[m] = fmaf(sp[m * 256 + k], wv, acc[m]);
    }
#pragma unroll
    for (int m = 0; m < 16; ++m) so[m * 512 + d] = acc[m];
  }
  __syncthreads();
  const float expa = __expf(a[0]);
  for (int half = 0; half < 2; ++half) {
    const int d = tid + half * 256;
    float out[16];
#pragma unroll
    for (int m = 0; m < 16; ++m) {
      const float win = __expf(-(float)(t0 + m) * expa);
      out[m] = so[m * 512 + d] * win;
    }
    float4* o4 = (float4*)(whT + (size_t)d * 4096 + t0);
    o4[0] = make_float4(out[0], out[1], out[2], out[3]);
    o4[1] = make_float4(out[4], out[5], out[6], out[7]);
    o4[2] = make_float4(out[8], out[9], out[10], out[11]);
    o4[3] = make_float4(out[12], out[13], out[14], out[15]);
  }
}

// ---------------- in-LDS 8192-pt FFT helpers (256 threads) ------------------
// Forward: radix-2 DIF, natural in -> bit-reversed out, twiddles e^{-i*}
DEVI void fft_fwd_dif(float* sre, float* sim, int tid) {
  for (int s = 12; s >= 0; --s) {
    const int len = 1 << s;
    const float inv = 1.0f / (float)len;
    for (int p = tid; p < 4096; p += 256) {
      const int j = p & (len - 1);
      const int i0 = ((p >> s) << (s + 1)) + j;
      const int i1 = i0 + len;
      const float ur = sre[i0], ui = sim[i0];
      const float vr = sre[i1], vi = sim[i1];
      sre[i0] = ur + vr; sim[i0] = ui + vi;
      const float dr = ur - vr, di = ui - vi;
      const float ang = -3.14159265358979323846f * (float)j * inv;
      float c, sn;
      __sincosf(ang, &sn, &c);
      sre[i1] = dr * c - di * sn;
      sim[i1] = dr * sn + di * c;
    }
    __syncthreads();
  }
}
// Inverse: radix-2 DIT, bit-reversed in -> natural out, twiddles e^{+i*}, unscaled
DEVI void fft_inv_dit(float* sre, float* sim, int tid) {
  for (int s = 0; s <= 12; ++s) {
    const int half = 1 << s;
    const float inv = 1.0f / (float)half;
    for (int p = tid; p < 4096; p += 256) {
      const int j = p & (half - 1);
      const int i0 = ((p >> s) << (s + 1)) + j;
      const int i1 = i0 + half;
      const float ang = 3.14159265358979323846f * (float)j * inv;
      float c, sn;
      __sincosf(ang, &sn, &c);
      const float xr = sre[i1], xi = sim[i1];
      const float vr = xr * c - xi * sn;
      const float vi = xr * sn + xi * c;
      const float ur = sre[i0], ui = sim[i0];
      sre[i0] = ur + vr; sim[i0] = ui + vi;
      sre[i1] = ur - vr; sim[i1] = ui - vi;
    }
    __syncthreads();
  }
}

// -------- filter FFT: 2 channels packed per block; store W/8192, natural k --
__global__ __launch_bounds__(256) void k_filter_fft(const float* __restrict__ whT,
                                                    float2* __restrict__ wfhT) {
  __shared__ float sre[8192];
  __shared__ float sim[8192];
  const int tid = threadIdx.x;
  const int d0 = blockIdx.x * 2, d1 = d0 + 1;
  const float* h0 = whT + (size_t)d0 * 4096;
  const float* h1 = whT + (size_t)d1 * 4096;
  for (int t = tid; t < 4096; t += 256) {
    sre[t] = h0[t]; sim[t] = h1[t];
    sre[4096 + t] = 0.f; sim[4096 + t] = 0.f;
  }
  __syncthreads();
  fft_fwd_dif(sre, sim, tid);
  const float sc = 1.0f / 8192.0f;
  for (int q = tid; q < 4096; q += 256) {
    if (q == 0) {
      // bin 0 at pos 0; bin 4096 at pos brev13(4096)=1 (both real-valued)
      wfhT[(size_t)d0 * 4097 + 0]    = make_float2(sre[0] * sc, 0.f);
      wfhT[(size_t)d1 * 4097 + 0]    = make_float2(sim[0] * sc, 0.f);
      wfhT[(size_t)d0 * 4097 + 4096] = make_float2(sre[1] * sc, 0.f);
      wfhT[(size_t)d1 * 4097 + 4096] = make_float2(sim[1] * sc, 0.f);
    } else {
      const int pk = __brev(q) >> 19;
      const int pm = __brev(8192 - q) >> 19;
      const float ar = sre[pk], ai = sim[pk], br = sre[pm], bi = sim[pm];
      wfhT[(size_t)d0 * 4097 + q] = make_float2(0.5f * (ar + br) * sc, 0.5f * (ai - bi) * sc);
      wfhT[(size_t)d1 * 4097 + q] = make_float2(0.5f * (ai + bi) * sc, 0.5f * (br - ar) * sc);
    }
  }
}

// ---------------- LN(z) + transpose to lnzT[b][d][t] ------------------------
__global__ __launch_bounds__(256) void k_ln_tr_z(const float* __restrict__ z,
                                                 const float* __restrict__ g,
                                                 const float* __restrict__ be,
                                                 float* __restrict__ lnzT) {
  __shared__ float sd[16 * 516];
  __shared__ float smu[16], srs[16];
  const int tid = threadIdx.x;
  const int b = blockIdx.y;
  const int t0 = blockIdx.x * 16;
  for (int i = tid; i < 16 * 128; i += 256) {
    const int row = i >> 7, c4 = i & 127;
    const float4 v = *(const float4*)(z + ((size_t)b * 4096 + t0 + row) * 512 + c4 * 4);
    *(float4*)(&sd[row * 516 + c4 * 4]) = v;
  }
  __syncthreads();
  const int r = tid >> 4, s = tid & 15;
  float sum = 0.f, sq = 0.f;
#pragma unroll
  for (int i = 0; i < 8; ++i) {
    const int c4 = s + 16 * i;
    const float4 v = *(const float4*)(&sd[r * 516 + c4 * 4]);
    sum += v.x + v.y + v.z + v.w;
    sq += v.x * v.x + v.y * v.y + v.z * v.z + v.w * v.w;
  }
#pragma unroll
  for (int off = 1; off < 16; off <<= 1) {
    sum += __shfl_xor(sum, off);
    sq += __shfl_xor(sq, off);
  }
  if (s == 0) {
    const float mu = sum * (1.f / 512.f);
    const float var = sq * (1.f / 512.f) - mu * mu;
    smu[r] = mu;
    srs[r] = rsqrtf(var + 1e-5f);
  }
  __syncthreads();
  for (int pass = 0; pass < 8; ++pass) {
    const int d = pass * 64 + (tid >> 2);
    const int q = tid & 3;
    const float gg = g[d], bb = be[d];
    float4 o;
    o.x = (sd[(q * 4 + 0) * 516 + d] - smu[q * 4 + 0]) * srs[q * 4 + 0] * gg + bb;
    o.y = (sd[(q * 4 + 1) * 516 + d] - smu[q * 4 + 1]) * srs[q * 4 + 1] * gg + bb;
    o.z = (sd[(q * 4 + 2) * 516 + d] - smu[q * 4 + 2]) * srs[q * 4 + 2] * gg + bb;
    o.w = (sd[(q * 4 + 3) * 516 + d] - smu[q * 4 + 3]) * srs[q * 4 + 3] * gg + bb;
    *(float4*)(lnzT + ((size_t)b * 512 + d) * 4096 + t0 + q * 4) = o;
  }
}

// ------- fused conv: fwdFFT(2ch packed) * W -> invFFT -> convT[b][d][t] -----
__global__ __launch_bounds__(256) void k_conv_fft(const float* __restrict__ lnzT,
                                                  const float2* __restrict__ wfhT,
                                                  float* __restrict__ convT) {
  __shared__ float sre[8192];
  __shared__ float sim[8192];
  const int tid = threadIdx.x;
  const int pr = blockIdx.x;
  const int b = blockIdx.y;
  const int d0 = pr * 2, d1 = d0 + 1;
  const float* z0 = lnzT + ((size_t)b * 512 + d0) * 4096;
  const float* z1 = lnzT + ((size_t)b * 512 + d1) * 4096;
  for (int t = tid; t < 4096; t += 256) {
    sre[t] = z0[t]; sim[t] = z1[t];
    sre[4096 + t] = 0.f; sim[4096 + t] = 0.f;
  }
  __syncthreads();
  fft_fwd_dif(sre, sim, tid);
  const float2* W0 = wfhT + (size_t)d0 * 4097;
  const float2* W1 = wfhT + (size_t)d1 * 4097;
  for (int q = tid; q < 4096; q += 256) {
    if (q == 0) {
      const float2 w10 = W0[0], w20 = W1[0];
      sre[0] = w10.x * sre[0]; sim[0] = w20.x * sim[0];
      const float2 w14 = W0[4096], w24 = W1[4096];
      sre[1] = w14.x * sre[1]; sim[1] = w24.x * sim[1];
    } else {
      const int pk = __brev(q) >> 19;
      const int pm = __brev(8192 - q) >> 19;
      const float ar = sre[pk], ai = sim[pk], br = sre[pm], bi = sim[pm];
      const float f1r = 0.5f * (ar + br), f1i = 0.5f * (ai - bi);
      const float f2r = 0.5f * (ai + bi), f2i = 0.5f * (br - ar);
      const float2 w1 = W0[q], w2 = W1[q];
      const float g1r = w1.x * f1r - w1.y * f1i, g1i = w1.x * f1i + w1.y * f1r;
      const float g2r = w2.x * f2r - w2.y * f2i, g2i = w2.x * f2i + w2.y * f2r;
      sre[pk] = g1r - g2i; sim[pk] = g1i + g2r;
      sre[pm] = g1r + g2i; sim[pm] = g2r - g1i;
    }
  }
  __syncthreads();
  fft_inv_dit(sre, sim, tid);
  float* o0 = convT + ((size_t)b * 512 + d0) * 4096;
  float* o1 = convT + ((size_t)b * 512 + d1) * 4096;
  for (int t = tid; t < 4096; t += 256) {
    o0[t] = sre[t];
    o1[t] = sim[t];
  }
}

// ------ fuse: cwhz = convT^T + z ; t1 = LN(cwhz) -> [b][t][d] rows ----------
__global__ __launch_bounds__(256) void k_fuse_t1(const float* __restrict__ convT,
                                                 const float* __restrict__ z,
                                                 const float* __restrict__ g,
                                                 const float* __restrict__ be,
                                                 float* __restrict__ t1) {
  __shared__ float sd[16 * 516];
  __shared__ float smu[16], srs[16];
  const int tid = threadIdx.x;
  const int b = blockIdx.y;
  const int t0 = blockIdx.x * 16;
  for (int pass = 0; pass < 8; ++pass) {
    const int d = pass * 64 + (tid >> 2);
    const int q = tid & 3;
    const float4 v = *(const float4*)(convT + ((size_t)b * 512 + d) * 4096 + t0 + q * 4);
    sd[(q * 4 + 0) * 516 + d] = v.x;
    sd[(q * 4 + 1) * 516 + d] = v.y;
    sd[(q * 4 + 2) * 516 + d] = v.z;
    sd[(q * 4 + 3) * 516 + d] = v.w;
  }
  __syncthreads();
  const int r = tid >> 4, s = tid & 15;
  const float* zr = z + ((size_t)b * 4096 + t0 + r) * 512;
  float sum = 0.f, sq = 0.f;
#pragma unroll
  for (int i = 0; i < 8; ++i) {
    const int c4 = s + 16 * i;
    const float4 zv = *(const float4*)(zr + c4 * 4);
    float* p = &sd[r * 516 + c4 * 4];
    const float v0 = p[0] + zv.x, v1 = p[1] + zv.y, v2 = p[2] + zv.z, v3 = p[3] + zv.w;
    p[0] = v0; p[1] = v1; p[2] = v2; p[3] = v3;
    sum += v0 + v1 + v2 + v3;
    sq += v0 * v0 + v1 * v1 + v2 * v2 + v3 * v3;
  }
#pragma unroll
  for (int off = 1; off < 16; off <<= 1) {
    sum += __shfl_xor(sum, off);
    sq += __shfl_xor(sq, off);
  }
  if (s == 0) {
    const float mu = sum * (1.f / 512.f);
    const float var = sq * (1.f / 512.f) - mu * mu;
    smu[r] = mu;
    srs[r] = rsqrtf(var + 1e-5f);
  }
  __syncthreads();
  for (int i = tid; i < 16 * 128; i += 256) {
    const int row = i >> 7, c4 = i & 127;
    const float mu = smu[row], rs = srs[row];
    const float4 gv = *(const float4*)(g + c4 * 4);
    const float4 bv = *(const float4*)(be + c4 * 4);
    const float* p = &sd[row * 516 + c4 * 4];
    float4 o;
    o.x = (p[0] - mu) * rs * gv.x + bv.x;
    o.y = (p[1] - mu) * rs * gv.y + bv.y;
    o.z = (p[2] - mu) * rs * gv.z + bv.z;
    o.w = (p[3] - mu) * rs * gv.w + bv.w;
    *(float4*)(t1 + ((size_t)b * 4096 + t0 + row) * 512 + c4 * 4) = o;
  }
}

// ---------------- f32 -> bf16 convert (grid-stride, float4-wise) ------------
__global__ __launch_bounds__(256) void k_cvt_bf16(const float* __restrict__ in,
                                                  unsigned short* __restrict__ out,
                                                  int n4) {
  const int stride = gridDim.x * 256;
  for (int i = blockIdx.x * 256 + threadIdx.x; i < n4; i += stride) {
    const float4 v = ((const float4*)in)[i];
    ushort4 o;
    o.x = to_bf16_bits(v.x);
    o.y = to_bf16_bits(v.y);
    o.z = to_bf16_bits(v.z);
    o.w = to_bf16_bits(v.w);
    ((ushort4*)out)[i] = o;
  }
}

// ---------------- LN(y) rows -> bf16 ----------------------------------------
__global__ __launch_bounds__(256) void k_lny(const float* __restrict__ y,
                                             const float* __restrict__ g,
                                             const float* __restrict__ be,
                                             unsigned short* __restrict__ out) {
  const int tid = threadIdx.x;
  const int lane = tid & 63, w = tid >> 6;
  const size_t row = (size_t)blockIdx.x * 4 + w;
  const float4* yr = (const float4*)(y + row * 512);
  const float4 v0 = yr[lane], v1 = yr[lane + 64];
  float sum = v0.x + v0.y + v0.z + v0.w + v1.x + v1.y + v1.z + v1.w;
  float sq = v0.x * v0.x + v0.y * v0.y + v0.z * v0.z + v0.w * v0.w +
             v1.x * v1.x + v1.y * v1.y + v1.z * v1.z + v1.w * v1.w;
#pragma unroll
  for (int off = 1; off < 64; off <<= 1) {
    sum += __shfl_xor(sum, off);
    sq += __shfl_xor(sq, off);
  }
  const float mu = sum * (1.f / 512.f);
  const float var = sq * (1.f / 512.f) - mu * mu;
  const float rs = rsqrtf(var + 1e-5f);
  const float4* g4 = (const float4*)g;
  const float4* b4 = (const float4*)be;
  const float4 g0 = g4[lane], g1 = g4[lane + 64];
  const float4 bb0 = b4[lane], bb1 = b4[lane + 64];
  ushort4 o0, o1;
  o0.x = to_bf16_bits((v0.x - mu) * rs * g0.x + bb0.x);
  o0.y = to_bf16_bits((v0.y - mu) * rs * g0.y + bb0.y);
  o0.z = to_bf16_bits((v0.z - mu) * rs * g0.z + bb0.z);
  o0.w = to_bf16_bits((v0.w - mu) * rs * g0.w + bb0.w);
  o1.x = to_bf16_bits((v1.x - mu) * rs * g1.x + bb1.x);
  o1.y = to_bf16_bits((v1.y - mu) * rs * g1.y + bb1.y);
  o1.z = to_bf16_bits((v1.z - mu) * rs * g1.z + bb1.z);
  o1.w = to_bf16_bits((v1.w - mu) * rs * g1.w + bb1.w);
  ((ushort4*)out)[row * 128 + lane] = o0;
  ((ushort4*)out)[row * 128 + lane + 64] = o1;
}

// ---------------- bf16 MFMA GEMM: C = A[M,K] @ B[N,K]^T + epi ---------------
// EPI 0: silu(v+bias) -> bf16    EPI 1: (v+bias)*extra -> f32
// EPI 2: (v+bias)+extra -> f32
template <int EPI>
__global__ __launch_bounds__(256) void k_gemm(const unsigned short* __restrict__ A,
                                              const unsigned short* __restrict__ Bw,
                                              const float* __restrict__ bias,
                                              const float* __restrict__ extra,
                                              void* __restrict__ Cout,
                                              int M, int N, int K) {
  __shared__ unsigned short sA[128 * 32];
  __shared__ unsigned short sB[128 * 32];
  const int tid = threadIdx.x;
  const int lane = tid & 63;
  const int w = tid >> 6;
  const int wr = w >> 1, wc = w & 1;
  const int m0 = blockIdx.y * 128, n0 = blockIdx.x * 128;
  f32x4 acc[4][4];
#pragma unroll
  for (int m = 0; m < 4; ++m)
#pragma unroll
    for (int n = 0; n < 4; ++n) acc[m][n] = (f32x4){0.f, 0.f, 0.f, 0.f};

  const int c_row = lane >> 2;
  const int c_off = (lane & 3) * 16;  // byte offset within 64B row
  const int nk = K >> 5;
  const int rA = lane & 15, kq = (lane >> 4) * 8;

  for (int kt = 0; kt < nk; ++kt) {
    __syncthreads();
    const int kb = kt * 32;
#pragma unroll
    for (int i = 0; i < 2; ++i) {
      const int ch = w * 2 + i;
      const int row = ch * 16 + c_row;
      gld_lds16((const char*)(A + (size_t)(m0 + row) * K + kb) + c_off,
                (char*)sA + ch * 1024);
      gld_lds16((const char*)(Bw + (size_t)(n0 + row) * K + kb) + c_off,
                (char*)sB + ch * 1024);
    }
    __syncthreads();
    bf16x8 af[4], bfv[4];
#pragma unroll
    for (int m = 0; m < 4; ++m)
      af[m] = *(const bf16x8*)(sA + (wr * 64 + m * 16 + rA) * 32 + kq);
#pragma unroll
    for (int n = 0; n < 4; ++n)
      bfv[n] = *(const bf16x8*)(sB + (wc * 64 + n * 16 + rA) * 32 + kq);
#pragma unroll
    for (int m = 0; m < 4; ++m)
#pragma unroll
      for (int n = 0; n < 4; ++n)
        acc[m][n] = __builtin_amdgcn_mfma_f32_16x16x32_bf16(af[m], bfv[n], acc[m][n], 0, 0, 0);
  }

  const int r0 = m0 + wr * 64 + (lane >> 4) * 4;
  const int c0 = n0 + wc * 64 + rA;
#pragma unroll
  for (int n = 0; n < 4; ++n) {
    const int cc = c0 + n * 16;
    const float bv = bias[cc];
#pragma unroll
    for (int m = 0; m < 4; ++m) {
#pragma unroll
      for (int j = 0; j < 4; ++j) {
        const int rr = r0 + m * 16 + j;
        const float v = acc[m][n][j] + bv;
        if constexpr (EPI == 0) {
          const float sv = v / (1.f + __expf(-v));
          ((unsigned short*)Cout)[(size_t)rr * N + cc] = to_bf16_bits(sv);
        } else if constexpr (EPI == 1) {
          ((float*)Cout)[(size_t)rr * N + cc] = v * extra[(size_t)rr * N + cc];
        } else {
          ((float*)Cout)[(size_t)rr * N + cc] = v + extra[(size_t)rr * N + cc];
        }
      }
    }
  }
}

// ---------------------------------------------------------------------------
extern "C" void kernel_launch(void* const* d_in, const int* in_sizes, int n_in,
                              void* d_out, int out_size, void* d_ws, size_t ws_size,
                              hipStream_t stream) {
  const float* z = (const float*)d_in[0];
  const float* x = (const float*)d_in[1];
  const float* pos = (const float*)d_in[2];
  const float* pos_w1 = (const float*)d_in[3];
  const float* pos_b1 = (const float*)d_in[4];
  const float* pos_w2 = (const float*)d_in[5];
  const float* pos_b2 = (const float*)d_in[6];
  const float* a = (const float*)d_in[7];
  const float* ffn_w1 = (const float*)d_in[8];
  const float* ffn_b1 = (const float*)d_in[9];
  const float* ffn_w2 = (const float*)d_in[10];
  const float* ffn_b2 = (const float*)d_in[11];
  const float* ffnx_w1 = (const float*)d_in[12];
  const float* ffnx_b1 = (const float*)d_in[13];
  const float* ffnx_w2 = (const float*)d_in[14];
  const float* ffnx_b2 = (const float*)d_in[15];
  const float* ln_g = (const float*)d_in[16];
  const float* ln_b = (const float*)d_in[17];
  float* outp = (float*)d_out;

  char* ws = (char*)d_ws;
  const size_t MiB = 1ull << 20;
  // phase-overlapped workspace (125 MiB total)
  float* p1 = (float*)(ws + 0);                               // 4 MiB (phase A)
  float* whT = (float*)(ws + 4 * MiB);                        // 8 MiB (phase A)
  unsigned short* wb_fx1 = (unsigned short*)(ws + 0);         // 1 MiB (after posffn2)
  unsigned short* wb_fx2 = (unsigned short*)(ws + 1 * MiB);
  unsigned short* wb_f1 = (unsigned short*)(ws + 2 * MiB);
  unsigned short* wb_f2 = (unsigned short*)(ws + 3 * MiB);
  float2* wfhT = (float2*)(ws + 12 * MiB);                    // 16.01 MiB
  unsigned short* xb = (unsigned short*)(ws + 12 * MiB);      // 16 MiB (after conv)
  float* lnzT = (float*)(ws + 29 * MiB);                      // 32 MiB
  float* yb = (float*)(ws + 29 * MiB);                        // 32 MiB (after conv)
  float* convT = (float*)(ws + 61 * MiB);                     // 32 MiB
  unsigned short* H = (unsigned short*)(ws + 61 * MiB);       // 32 MiB (after fuse)
  float* t1 = (float*)(ws + 93 * MiB);                        // 32 MiB
  unsigned short* ylnb = (unsigned short*)(ws + 93 * MiB);    // 16 MiB (after gemm2)

  // filter path
  k_posffn1<<<256, 256, 0, stream>>>(pos, pos_w1, pos_b1, p1);
  k_posffn2<<<256, 256, 0, stream>>>(p1, pos_w2, pos_b2, a, whT);
  k_filter_fft<<<256, 256, 0, stream>>>(whT, wfhT);
  // weight converts (p1 region now dead)
  k_cvt_bf16<<<256, 256, 0, stream>>>(ffnx_w1, wb_fx1, (1024 * 512) / 4);
  k_cvt_bf16<<<256, 256, 0, stream>>>(ffnx_w2, wb_fx2, (512 * 1024) / 4);
  k_cvt_bf16<<<256, 256, 0, stream>>>(ffn_w1, wb_f1, (1024 * 512) / 4);
  k_cvt_bf16<<<256, 256, 0, stream>>>(ffn_w2, wb_f2, (512 * 1024) / 4);
  // data path: LN+transpose -> FFT conv -> transpose back + LN
  k_ln_tr_z<<<dim3(256, 4), 256, 0, stream>>>(z, ln_g, ln_b, lnzT);
  k_conv_fft<<<dim3(256, 4), 256, 0, stream>>>(lnzT, wfhT, convT);
  k_fuse_t1<<<dim3(256, 4), 256, 0, stream>>>(convT, z, ln_g, ln_b, t1);
  // FFN chain (bf16 MFMA)
  k_cvt_bf16<<<4096, 256, 0, stream>>>(x, xb, (MSEQ * 512) / 4);
  k_gemm<0><<<dim3(8, 128), 256, 0, stream>>>(xb, wb_fx1, ffnx_b1, nullptr, H, MSEQ, 1024, 512);
  k_gemm<1><<<dim3(4, 128), 256, 0, stream>>>(H, wb_fx2, ffnx_b2, t1, yb, MSEQ, 512, 1024);
  k_lny<<<4096, 256, 0, stream>>>(yb, ln_g, ln_b, ylnb);
  k_gemm<0><<<dim3(8, 128), 256, 0, stream>>>(ylnb, wb_f1, ffn_b1, nullptr, H, MSEQ, 1024, 512);
  k_gemm<2><<<dim3(4, 128), 256, 0, stream>>>(H, wb_f2, ffn_b2, yb, outp, MSEQ, 512, 1024);
}

// Round 4
// 500.344 us; speedup vs baseline: 1.1878x; 1.1878x over previous
//
#include <hip/hip_runtime.h>
#include <hip/hip_bf16.h>
#include <stdint.h>

// ---------------------------------------------------------------------------
// HyenaBaseBlock: LN -> FFT causal conv (n=8192) -> +z -> LN -> *FFN(x) -> LN
// -> FFN -> +residual.  f32 fused-radix-2^2 FFT in LDS, bf16 MFMA GEMMs.
// ---------------------------------------------------------------------------

typedef __attribute__((ext_vector_type(8))) short bf16x8;
typedef __attribute__((ext_vector_type(4))) float f32x4;
typedef const __attribute__((address_space(1))) void* as1cv;
typedef __attribute__((address_space(3))) void* as3v;

#define DEVI __device__ __forceinline__

#define B_ 4
#define L_ 4096
#define D_ 512
#define MSEQ 16384   // B_*L_

// padded LDS word address: spreads stride-32/128 patterns across banks
#define PADW(e) ((e) + ((e) >> 4) + ((e) >> 7))
#define SPAD 8768          // PADW(8191)+1 = 8766, rounded up

DEVI void gld_lds16(const void* g, void* l) {
  __builtin_amdgcn_global_load_lds((as1cv)(uintptr_t)g, (as3v)(uintptr_t)l, 16, 0, 0);
}

DEVI unsigned short to_bf16_bits(float v) {
  __hip_bfloat16 h = __float2bfloat16(v);
  return *reinterpret_cast<unsigned short*>(&h);
}

// twiddle lookup: e^{-2*pi*i*k/8192} for k in [0,2048); table holds k=0..1024
DEVI float2 twget(const float2* t, int k) {
  if (k <= 1024) return t[k];
  const float2 v = t[2048 - k];
  return make_float2(-v.y, -v.x);   // = -i * conj(t[2048-k])
}

DEVI void tw_fill(float2* twl, int tid, int nthr) {
  for (int m = tid; m <= 1024; m += nthr) {
    float sn, cs;
    __sincosf((float)m * (-3.14159265358979323846f / 4096.f), &sn, &cs);
    twl[m] = make_float2(cs, sn);
  }
}

// ---- fused forward DIF pair (s, s-1); ZH: top half (c,d inputs) are zero ---
template <bool ZH>
DEVI void fft_fwd_fused(float* sre, float* sim, const float2* twl, const int s, const int tid) {
  const int h = 1 << (s - 1);
  const int sh = 12 - s;
  for (int g = tid; g < 2048; g += 512) {
    const int j = g & (h - 1);
    const int grp = g >> (s - 1);
    const int ia = (grp << (s + 1)) + j;
    const int pa = PADW(ia), pb = PADW(ia + h), pc = PADW(ia + 2 * h), pd = PADW(ia + 3 * h);
    const float ar = sre[pa], ai = sim[pa];
    const float br = sre[pb], bi = sim[pb];
    const float2 w1 = twget(twl, j << sh);
    const float w3r = w1.x * w1.x - w1.y * w1.y;
    const float w3i = 2.f * w1.x * w1.y;
    float t0r, t0i, t1r, t1i, t2r, t2i, t3r, t3i;
    if (ZH) {
      t0r = ar; t0i = ai;
      t1r = ar * w1.x - ai * w1.y;  t1i = ar * w1.y + ai * w1.x;
      t2r = br; t2i = bi;
      t3r = br * w1.y + bi * w1.x;  t3i = bi * w1.y - br * w1.x;   // b * (-i w1)
    } else {
      const float cr = sre[pc], ci = sim[pc];
      const float dr = sre[pd], di = sim[pd];
      t0r = ar + cr; t0i = ai + ci;
      const float u0r = ar - cr, u0i = ai - ci;
      t1r = u0r * w1.x - u0i * w1.y;  t1i = u0r * w1.y + u0i * w1.x;
      t2r = br + dr; t2i = bi + di;
      const float u1r = br - dr, u1i = bi - di;
      t3r = u1r * w1.y + u1i * w1.x;  t3i = u1i * w1.y - u1r * w1.x; // (b-d)*(-i w1)
    }
    // stage s-1 (twiddle W3 = W1^2)
    sre[pa] = t0r + t2r; sim[pa] = t0i + t2i;
    float vr = t0r - t2r, vi = t0i - t2i;
    sre[pb] = vr * w3r - vi * w3i; sim[pb] = vr * w3i + vi * w3r;
    sre[pc] = t1r + t3r; sim[pc] = t1i + t3i;
    vr = t1r - t3r; vi = t1i - t3i;
    sre[pd] = vr * w3r - vi * w3i; sim[pd] = vr * w3i + vi * w3r;
  }
  __syncthreads();
}

// ---- fused inverse DIT pair (s, s+1); DH: drop stores to upper half --------
template <bool DH>
DEVI void fft_inv_fused(float* sre, float* sim, const float2* twl, const int s, const int tid) {
  const int h = 1 << s;
  const int sh = 11 - s;
  for (int g = tid; g < 2048; g += 512) {
    const int j = g & (h - 1);
    const int grp = g >> s;
    const int ia = (grp << (s + 2)) + j;
    const int pa = PADW(ia), pb = PADW(ia + h), pc = PADW(ia + 2 * h), pd = PADW(ia + 3 * h);
    const float ar = sre[pa], ai = sim[pa];
    const float br = sre[pb], bi = sim[pb];
    const float cr = sre[pc], ci = sim[pc];
    const float dr = sre[pd], di = sim[pd];
    const float2 wc = twget(twl, j << sh);
    const float w2r = wc.x, w2i = -wc.y;                 // conj -> e^{+i...}
    const float w1r = w2r * w2r - w2i * w2i, w1i = 2.f * w2r * w2i;
    // stage s
    const float vbr = br * w1r - bi * w1i, vbi = br * w1i + bi * w1r;
    const float t0r = ar + vbr, t0i = ai + vbi, t1r = ar - vbr, t1i = ai - vbi;
    const float vdr = dr * w1r - di * w1i, vdi = dr * w1i + di * w1r;
    const float t2r = cr + vdr, t2i = ci + vdi, t3r = cr - vdr, t3i = ci - vdi;
    // stage s+1
    const float vcr = t2r * w2r - t2i * w2i, vci = t2r * w2i + t2i * w2r;
    sre[pa] = t0r + vcr; sim[pa] = t0i + vci;
    if (!DH) { sre[pc] = t0r - vcr; sim[pc] = t0i - vci; }
    const float vd2r = -t3r * w2i - t3i * w2r, vd2i = t3r * w2r - t3i * w2i; // t3*(i w2)
    sre[pb] = t1r + vd2r; sim[pb] = t1i + vd2i;
    if (!DH) { sre[pd] = t1r - vd2r; sim[pd] = t1i - vd2i; }
  }
  __syncthreads();
}

// ---- single trivial stage 0 (twiddle = 1), shared by fwd tail / inv head ---
DEVI void fft_stage0(float* sre, float* sim, const int tid) {
  for (int p = tid; p < 4096; p += 512) {
    const int i0 = PADW(2 * p), i1 = PADW(2 * p + 1);
    const float ur = sre[i0], ui = sim[i0], vr = sre[i1], vi = sim[i1];
    sre[i0] = ur + vr; sim[i0] = ui + vi;
    sre[i1] = ur - vr; sim[i1] = ui - vi;
  }
  __syncthreads();
}

DEVI void fft_fwd_all(float* sre, float* sim, const float2* twl, const int tid) {
  fft_fwd_fused<true>(sre, sim, twl, 12, tid);
  fft_fwd_fused<false>(sre, sim, twl, 10, tid);
  fft_fwd_fused<false>(sre, sim, twl, 8, tid);
  fft_fwd_fused<false>(sre, sim, twl, 6, tid);
  fft_fwd_fused<false>(sre, sim, twl, 4, tid);
  fft_fwd_fused<false>(sre, sim, twl, 2, tid);
  fft_stage0(sre, sim, tid);
}

DEVI void fft_inv_all(float* sre, float* sim, const float2* twl, const int tid) {
  fft_stage0(sre, sim, tid);
  fft_inv_fused<false>(sre, sim, twl, 1, tid);
  fft_inv_fused<false>(sre, sim, twl, 3, tid);
  fft_inv_fused<false>(sre, sim, twl, 5, tid);
  fft_inv_fused<false>(sre, sim, twl, 7, tid);
  fft_inv_fused<false>(sre, sim, twl, 9, tid);
  fft_inv_fused<true>(sre, sim, twl, 11, tid);   // only t<4096 outputs needed
}

// ---------------- pos FFN layer 1: p1 = silu(pos @ w1^T + b1)  [4096,256] ---
__global__ __launch_bounds__(256) void k_posffn1(const float* __restrict__ pos,
                                                 const float* __restrict__ w1,
                                                 const float* __restrict__ b1,
                                                 float* __restrict__ p1) {
  __shared__ float sp[16 * 128];
  const int tid = threadIdx.x;
  const int m0 = blockIdx.x * 16;
  const float4* src = (const float4*)(pos + (size_t)m0 * 128);
  float4* dst = (float4*)sp;
  for (int i = tid; i < 512; i += 256) dst[i] = src[i];
  __syncthreads();
  const int n = tid;
  float acc[16];
  const float bias = b1[n];
#pragma unroll
  for (int m = 0; m < 16; ++m) acc[m] = bias;
  const float* w = w1 + (size_t)n * 128;
  for (int k = 0; k < 128; ++k) {
    const float wv = w[k];
#pragma unroll
    for (int m = 0; m < 16; ++m) acc[m] = fmaf(sp[m * 128 + k], wv, acc[m]);
  }
#pragma unroll
  for (int m = 0; m < 16; ++m) {
    const float v = acc[m];
    p1[(size_t)(m0 + m) * 256 + n] = v / (1.f + __expf(-v));
  }
}

// ---- pos FFN layer 2 + window, write transposed whT[d][t] = win[t]*h[t][d] -
__global__ __launch_bounds__(256) void k_posffn2(const float* __restrict__ p1,
                                                 const float* __restrict__ w2,
                                                 const float* __restrict__ b2,
                                                 const float* __restrict__ a,
                                                 float* __restrict__ whT) {
  __shared__ float sp[16 * 256];
  __shared__ float so[16 * 512];
  const int tid = threadIdx.x;
  const int t0 = blockIdx.x * 16;
  const float4* src = (const float4*)(p1 + (size_t)t0 * 256);
  float4* dst = (float4*)sp;
  for (int i = tid; i < 1024; i += 256) dst[i] = src[i];
  __syncthreads();
  for (int half = 0; half < 2; ++half) {
    const int d = tid + half * 256;
    float acc[16];
    const float bias = b2[d];
#pragma unroll
    for (int m = 0; m < 16; ++m) acc[m] = bias;
    const float* w = w2 + (size_t)d * 256;
    for (int k = 0; k < 256; ++k) {
      const float wv = w[k];
#pragma unroll
      for (int m = 0; m < 16; ++m) acc[m] = fmaf(sp[m * 256 + k], wv, acc[m]);
    }
#pragma unroll
    for (int m = 0; m < 16; ++m) so[m * 512 + d] = acc[m];
  }
  __syncthreads();
  const float expa = __expf(a[0]);
  for (int half = 0; half < 2; ++half) {
    const int d = tid + half * 256;
    float out[16];
#pragma unroll
    for (int m = 0; m < 16; ++m) {
      const float win = __expf(-(float)(t0 + m) * expa);
      out[m] = so[m * 512 + d] * win;
    }
    float4* o4 = (float4*)(whT + (size_t)d * 4096 + t0);
    o4[0] = make_float4(out[0], out[1], out[2], out[3]);
    o4[1] = make_float4(out[4], out[5], out[6], out[7]);
    o4[2] = make_float4(out[8], out[9], out[10], out[11]);
    o4[3] = make_float4(out[12], out[13], out[14], out[15]);
  }
}

// -------- filter FFT: 2 channels packed per block; store W/8192, natural k --
__global__ __launch_bounds__(512) void k_filter_fft(const float* __restrict__ whT,
                                                    float2* __restrict__ wfhT) {
  __shared__ float sre[SPAD];
  __shared__ float sim[SPAD];
  __shared__ float2 twl[1025];
  const int tid = threadIdx.x;
  tw_fill(twl, tid, 512);
  const int d0 = blockIdx.x * 2, d1 = d0 + 1;
  const float* h0 = whT + (size_t)d0 * 4096;
  const float* h1 = whT + (size_t)d1 * 4096;
  for (int t4 = tid; t4 < 1024; t4 += 512) {
    const float4 v0 = ((const float4*)h0)[t4];
    const float4 v1 = ((const float4*)h1)[t4];
    const int p = PADW(4 * t4);
    sre[p] = v0.x; sre[p + 1] = v0.y; sre[p + 2] = v0.z; sre[p + 3] = v0.w;
    sim[p] = v1.x; sim[p + 1] = v1.y; sim[p + 2] = v1.z; sim[p + 3] = v1.w;
  }
  __syncthreads();
  fft_fwd_all(sre, sim, twl, tid);
  const float sc = 1.0f / 8192.0f;
  const int lane = tid & 63;
  const int rl = __brev(lane) >> 26;
  const int qb = tid & ~63;
  for (int it = 0; it < 8; ++it) {
    const int q = it * 512 + qb + rl;
    if (q == 0) {
      // bin 0 at pos 0; bin 4096 at bitrev pos 1 (both real-valued)
      wfhT[(size_t)d0 * 4097 + 0]    = make_float2(sre[PADW(0)] * sc, 0.f);
      wfhT[(size_t)d1 * 4097 + 0]    = make_float2(sim[PADW(0)] * sc, 0.f);
      wfhT[(size_t)d0 * 4097 + 4096] = make_float2(sre[PADW(1)] * sc, 0.f);
      wfhT[(size_t)d1 * 4097 + 4096] = make_float2(sim[PADW(1)] * sc, 0.f);
    } else {
      const int pk = PADW(__brev(q) >> 19);
      const int pm = PADW(__brev(8192 - q) >> 19);
      const float ar = sre[pk], ai = sim[pk], br = sre[pm], bi = sim[pm];
      wfhT[(size_t)d0 * 4097 + q] = make_float2(0.5f * (ar + br) * sc, 0.5f * (ai - bi) * sc);
      wfhT[(size_t)d1 * 4097 + q] = make_float2(0.5f * (ai + bi) * sc, 0.5f * (br - ar) * sc);
    }
  }
}

// ---------------- LN(z) + transpose to lnzT[b][d][t] ------------------------
__global__ __launch_bounds__(256) void k_ln_tr_z(const float* __restrict__ z,
                                                 const float* __restrict__ g,
                                                 const float* __restrict__ be,
                                                 float* __restrict__ lnzT) {
  __shared__ float sd[16 * 516];
  __shared__ float smu[16], srs[16];
  const int tid = threadIdx.x;
  const int b = blockIdx.y;
  const int t0 = blockIdx.x * 16;
  for (int i = tid; i < 16 * 128; i += 256) {
    const int row = i >> 7, c4 = i & 127;
    const float4 v = *(const float4*)(z + ((size_t)b * 4096 + t0 + row) * 512 + c4 * 4);
    *(float4*)(&sd[row * 516 + c4 * 4]) = v;
  }
  __syncthreads();
  const int r = tid >> 4, s = tid & 15;
  float sum = 0.f, sq = 0.f;
#pragma unroll
  for (int i = 0; i < 8; ++i) {
    const int c4 = s + 16 * i;
    const float4 v = *(const float4*)(&sd[r * 516 + c4 * 4]);
    sum += v.x + v.y + v.z + v.w;
    sq += v.x * v.x + v.y * v.y + v.z * v.z + v.w * v.w;
  }
#pragma unroll
  for (int off = 1; off < 16; off <<= 1) {
    sum += __shfl_xor(sum, off);
    sq += __shfl_xor(sq, off);
  }
  if (s == 0) {
    const float mu = sum * (1.f / 512.f);
    const float var = sq * (1.f / 512.f) - mu * mu;
    smu[r] = mu;
    srs[r] = rsqrtf(var + 1e-5f);
  }
  __syncthreads();
  for (int pass = 0; pass < 8; ++pass) {
    const int d = pass * 64 + (tid >> 2);
    const int q = tid & 3;
    const float gg = g[d], bb = be[d];
    float4 o;
    o.x = (sd[(q * 4 + 0) * 516 + d] - smu[q * 4 + 0]) * srs[q * 4 + 0] * gg + bb;
    o.y = (sd[(q * 4 + 1) * 516 + d] - smu[q * 4 + 1]) * srs[q * 4 + 1] * gg + bb;
    o.z = (sd[(q * 4 + 2) * 516 + d] - smu[q * 4 + 2]) * srs[q * 4 + 2] * gg + bb;
    o.w = (sd[(q * 4 + 3) * 516 + d] - smu[q * 4 + 3]) * srs[q * 4 + 3] * gg + bb;
    *(float4*)(lnzT + ((size_t)b * 512 + d) * 4096 + t0 + q * 4) = o;
  }
}

// ------- fused conv: fwdFFT(2ch packed) * W -> invFFT -> convT[b][d][t] -----
__global__ __launch_bounds__(512) void k_conv_fft(const float* __restrict__ lnzT,
                                                  const float2* __restrict__ wfhT,
                                                  float* __restrict__ convT) {
  __shared__ float sre[SPAD];
  __shared__ float sim[SPAD];
  __shared__ float2 twl[1025];
  const int tid = threadIdx.x;
  tw_fill(twl, tid, 512);
  const int d0 = blockIdx.x * 2, d1 = d0 + 1;
  const int b = blockIdx.y;
  const float* z0 = lnzT + ((size_t)b * 512 + d0) * 4096;
  const float* z1 = lnzT + ((size_t)b * 512 + d1) * 4096;
  for (int t4 = tid; t4 < 1024; t4 += 512) {
    const float4 v0 = ((const float4*)z0)[t4];
    const float4 v1 = ((const float4*)z1)[t4];
    const int p = PADW(4 * t4);
    sre[p] = v0.x; sre[p + 1] = v0.y; sre[p + 2] = v0.z; sre[p + 3] = v0.w;
    sim[p] = v1.x; sim[p + 1] = v1.y; sim[p + 2] = v1.z; sim[p + 3] = v1.w;
  }
  __syncthreads();
  fft_fwd_all(sre, sim, twl, tid);  // first pass treats top half as zero
  const float2* W0 = wfhT + (size_t)d0 * 4097;
  const float2* W1 = wfhT + (size_t)d1 * 4097;
  const int lane = tid & 63;
  const int rl = __brev(lane) >> 26;
  const int qb = tid & ~63;
  for (int it = 0; it < 8; ++it) {
    const int q = it * 512 + qb + rl;
    if (q == 0) {
      const float2 w10 = W0[0], w20 = W1[0];
      sre[PADW(0)] *= w10.x; sim[PADW(0)] *= w20.x;
      const float2 w14 = W0[4096], w24 = W1[4096];
      sre[PADW(1)] *= w14.x; sim[PADW(1)] *= w24.x;
    } else {
      const int pk = PADW(__brev(q) >> 19);
      const int pm = PADW(__brev(8192 - q) >> 19);
      const float ar = sre[pk], ai = sim[pk], br = sre[pm], bi = sim[pm];
      const float f1r = 0.5f * (ar + br), f1i = 0.5f * (ai - bi);
      const float f2r = 0.5f * (ai + bi), f2i = 0.5f * (br - ar);
      const float2 w1 = W0[q], w2 = W1[q];
      const float g1r = w1.x * f1r - w1.y * f1i, g1i = w1.x * f1i + w1.y * f1r;
      const float g2r = w2.x * f2r - w2.y * f2i, g2i = w2.x * f2i + w2.y * f2r;
      sre[pk] = g1r - g2i; sim[pk] = g1i + g2r;
      sre[pm] = g1r + g2i; sim[pm] = g2r - g1i;
    }
  }
  __syncthreads();
  fft_inv_all(sre, sim, twl, tid);
  float* o0 = convT + ((size_t)b * 512 + d0) * 4096;
  float* o1 = convT + ((size_t)b * 512 + d1) * 4096;
  for (int t4 = tid; t4 < 1024; t4 += 512) {
    const int p = PADW(4 * t4);
    ((float4*)o0)[t4] = make_float4(sre[p], sre[p + 1], sre[p + 2], sre[p + 3]);
    ((float4*)o1)[t4] = make_float4(sim[p], sim[p + 1], sim[p + 2], sim[p + 3]);
  }
}

// ------ fuse: cwhz = convT^T + z ; t1 = LN(cwhz) -> [b][t][d] rows ----------
__global__ __launch_bounds__(256) void k_fuse_t1(const float* __restrict__ convT,
                                                 const float* __restrict__ z,
                                                 const float* __restrict__ g,
                                                 const float* __restrict__ be,
                                                 float* __restrict__ t1) {
  __shared__ float sd[16 * 516];
  __shared__ float smu[16], srs[16];
  const int tid = threadIdx.x;
  const int b = blockIdx.y;
  const int t0 = blockIdx.x * 16;
  for (int pass = 0; pass < 8; ++pass) {
    const int d = pass * 64 + (tid >> 2);
    const int q = tid & 3;
    const float4 v = *(const float4*)(convT + ((size_t)b * 512 + d) * 4096 + t0 + q * 4);
    sd[(q * 4 + 0) * 516 + d] = v.x;
    sd[(q * 4 + 1) * 516 + d] = v.y;
    sd[(q * 4 + 2) * 516 + d] = v.z;
    sd[(q * 4 + 3) * 516 + d] = v.w;
  }
  __syncthreads();
  const int r = tid >> 4, s = tid & 15;
  const float* zr = z + ((size_t)b * 4096 + t0 + r) * 512;
  float sum = 0.f, sq = 0.f;
#pragma unroll
  for (int i = 0; i < 8; ++i) {
    const int c4 = s + 16 * i;
    const float4 zv = *(const float4*)(zr + c4 * 4);
    float* p = &sd[r * 516 + c4 * 4];
    const float v0 = p[0] + zv.x, v1 = p[1] + zv.y, v2 = p[2] + zv.z, v3 = p[3] + zv.w;
    p[0] = v0; p[1] = v1; p[2] = v2; p[3] = v3;
    sum += v0 + v1 + v2 + v3;
    sq += v0 * v0 + v1 * v1 + v2 * v2 + v3 * v3;
  }
#pragma unroll
  for (int off = 1; off < 16; off <<= 1) {
    sum += __shfl_xor(sum, off);
    sq += __shfl_xor(sq, off);
  }
  if (s == 0) {
    const float mu = sum * (1.f / 512.f);
    const float var = sq * (1.f / 512.f) - mu * mu;
    smu[r] = mu;
    srs[r] = rsqrtf(var + 1e-5f);
  }
  __syncthreads();
  for (int i = tid; i < 16 * 128; i += 256) {
    const int row = i >> 7, c4 = i & 127;
    const float mu = smu[row], rs = srs[row];
    const float4 gv = *(const float4*)(g + c4 * 4);
    const float4 bv = *(const float4*)(be + c4 * 4);
    const float* p = &sd[row * 516 + c4 * 4];
    float4 o;
    o.x = (p[0] - mu) * rs * gv.x + bv.x;
    o.y = (p[1] - mu) * rs * gv.y + bv.y;
    o.z = (p[2] - mu) * rs * gv.z + bv.z;
    o.w = (p[3] - mu) * rs * gv.w + bv.w;
    *(float4*)(t1 + ((size_t)b * 4096 + t0 + row) * 512 + c4 * 4) = o;
  }
}

// ---------------- f32 -> bf16 convert (grid-stride, float4-wise) ------------
__global__ __launch_bounds__(256) void k_cvt_bf16(const float* __restrict__ in,
                                                  unsigned short* __restrict__ out,
                                                  int n4) {
  const int stride = gridDim.x * 256;
  for (int i = blockIdx.x * 256 + threadIdx.x; i < n4; i += stride) {
    const float4 v = ((const float4*)in)[i];
    ushort4 o;
    o.x = to_bf16_bits(v.x);
    o.y = to_bf16_bits(v.y);
    o.z = to_bf16_bits(v.z);
    o.w = to_bf16_bits(v.w);
    ((ushort4*)out)[i] = o;
  }
}

// ---------------- LN(y) rows -> bf16 ----------------------------------------
__global__ __launch_bounds__(256) void k_lny(const float* __restrict__ y,
                                             const float* __restrict__ g,
                                             const float* __restrict__ be,
                                             unsigned short* __restrict__ out) {
  const int tid = threadIdx.x;
  const int lane = tid & 63, w = tid >> 6;
  const size_t row = (size_t)blockIdx.x * 4 + w;
  const float4* yr = (const float4*)(y + row * 512);
  const float4 v0 = yr[lane], v1 = yr[lane + 64];
  float sum = v0.x + v0.y + v0.z + v0.w + v1.x + v1.y + v1.z + v1.w;
  float sq = v0.x * v0.x + v0.y * v0.y + v0.z * v0.z + v0.w * v0.w +
             v1.x * v1.x + v1.y * v1.y + v1.z * v1.z + v1.w * v1.w;
#pragma unroll
  for (int off = 1; off < 64; off <<= 1) {
    sum += __shfl_xor(sum, off);
    sq += __shfl_xor(sq, off);
  }
  const float mu = sum * (1.f / 512.f);
  const float var = sq * (1.f / 512.f) - mu * mu;
  const float rs = rsqrtf(var + 1e-5f);
  const float4* g4 = (const float4*)g;
  const float4* b4 = (const float4*)be;
  const float4 g0 = g4[lane], g1 = g4[lane + 64];
  const float4 bb0 = b4[lane], bb1 = b4[lane + 64];
  ushort4 o0, o1;
  o0.x = to_bf16_bits((v0.x - mu) * rs * g0.x + bb0.x);
  o0.y = to_bf16_bits((v0.y - mu) * rs * g0.y + bb0.y);
  o0.z = to_bf16_bits((v0.z - mu) * rs * g0.z + bb0.z);
  o0.w = to_bf16_bits((v0.w - mu) * rs * g0.w + bb0.w);
  o1.x = to_bf16_bits((v1.x - mu) * rs * g1.x + bb1.x);
  o1.y = to_bf16_bits((v1.y - mu) * rs * g1.y + bb1.y);
  o1.z = to_bf16_bits((v1.z - mu) * rs * g1.z + bb1.z);
  o1.w = to_bf16_bits((v1.w - mu) * rs * g1.w + bb1.w);
  ((ushort4*)out)[row * 128 + lane] = o0;
  ((ushort4*)out)[row * 128 + lane + 64] = o1;
}

// ---------------- bf16 MFMA GEMM: C = A[M,K] @ B[N,K]^T + epi ---------------
// EPI 0: silu(v+bias) -> bf16    EPI 1: (v+bias)*extra -> f32
// EPI 2: (v+bias)+extra -> f32
template <int EPI>
__global__ __launch_bounds__(256) void k_gemm(const unsigned short* __restrict__ A,
                                              const unsigned short* __restrict__ Bw,
                                              const float* __restrict__ bias,
                                              const float* __restrict__ extra,
                                              void* __restrict__ Cout,
                                              int M, int N, int K) {
  __shared__ unsigned short sA[128 * 32];
  __shared__ unsigned short sB[128 * 32];
  const int tid = threadIdx.x;
  const int lane = tid & 63;
  const int w = tid >> 6;
  const int wr = w >> 1, wc = w & 1;
  const int m0 = blockIdx.y * 128, n0 = blockIdx.x * 128;
  f32x4 acc[4][4];
#pragma unroll
  for (int m = 0; m < 4; ++m)
#pragma unroll
    for (int n = 0; n < 4; ++n) acc[m][n] = (f32x4){0.f, 0.f, 0.f, 0.f};

  const int c_row = lane >> 2;
  const int c_off = (lane & 3) * 16;  // byte offset within 64B row
  const int nk = K >> 5;
  const int rA = lane & 15, kq = (lane >> 4) * 8;

  for (int kt = 0; kt < nk; ++kt) {
    __syncthreads();
    const int kb = kt * 32;
#pragma unroll
    for (int i = 0; i < 2; ++i) {
      const int ch = w * 2 + i;
      const int row = ch * 16 + c_row;
      gld_lds16((const char*)(A + (size_t)(m0 + row) * K + kb) + c_off,
                (char*)sA + ch * 1024);
      gld_lds16((const char*)(Bw + (size_t)(n0 + row) * K + kb) + c_off,
                (char*)sB + ch * 1024);
    }
    __syncthreads();
    bf16x8 af[4], bfv[4];
#pragma unroll
    for (int m = 0; m < 4; ++m)
      af[m] = *(const bf16x8*)(sA + (wr * 64 + m * 16 + rA) * 32 + kq);
#pragma unroll
    for (int n = 0; n < 4; ++n)
      bfv[n] = *(const bf16x8*)(sB + (wc * 64 + n * 16 + rA) * 32 + kq);
#pragma unroll
    for (int m = 0; m < 4; ++m)
#pragma unroll
      for (int n = 0; n < 4; ++n)
        acc[m][n] = __builtin_amdgcn_mfma_f32_16x16x32_bf16(af[m], bfv[n], acc[m][n], 0, 0, 0);
  }

  const int r0 = m0 + wr * 64 + (lane >> 4) * 4;
  const int c0 = n0 + wc * 64 + rA;
#pragma unroll
  for (int n = 0; n < 4; ++n) {
    const int cc = c0 + n * 16;
    const float bv = bias[cc];
#pragma unroll
    for (int m = 0; m < 4; ++m) {
#pragma unroll
      for (int j = 0; j < 4; ++j) {
        const int rr = r0 + m * 16 + j;
        const float v = acc[m][n][j] + bv;
        if constexpr (EPI == 0) {
          const float sv = v / (1.f + __expf(-v));
          ((unsigned short*)Cout)[(size_t)rr * N + cc] = to_bf16_bits(sv);
        } else if constexpr (EPI == 1) {
          ((float*)Cout)[(size_t)rr * N + cc] = v * extra[(size_t)rr * N + cc];
        } else {
          ((float*)Cout)[(size_t)rr * N + cc] = v + extra[(size_t)rr * N + cc];
        }
      }
    }
  }
}

// ---------------------------------------------------------------------------
extern "C" void kernel_launch(void* const* d_in, const int* in_sizes, int n_in,
                              void* d_out, int out_size, void* d_ws, size_t ws_size,
                              hipStream_t stream) {
  const float* z = (const float*)d_in[0];
  const float* x = (const float*)d_in[1];
  const float* pos = (const float*)d_in[2];
  const float* pos_w1 = (const float*)d_in[3];
  const float* pos_b1 = (const float*)d_in[4];
  const float* pos_w2 = (const float*)d_in[5];
  const float* pos_b2 = (const float*)d_in[6];
  const float* a = (const float*)d_in[7];
  const float* ffn_w1 = (const float*)d_in[8];
  const float* ffn_b1 = (const float*)d_in[9];
  const float* ffn_w2 = (const float*)d_in[10];
  const float* ffn_b2 = (const float*)d_in[11];
  const float* ffnx_w1 = (const float*)d_in[12];
  const float* ffnx_b1 = (const float*)d_in[13];
  const float* ffnx_w2 = (const float*)d_in[14];
  const float* ffnx_b2 = (const float*)d_in[15];
  const float* ln_g = (const float*)d_in[16];
  const float* ln_b = (const float*)d_in[17];
  float* outp = (float*)d_out;

  char* ws = (char*)d_ws;
  const size_t MiB = 1ull << 20;
  // phase-overlapped workspace (125 MiB total)
  float* p1 = (float*)(ws + 0);                               // 4 MiB (phase A)
  float* whT = (float*)(ws + 4 * MiB);                        // 8 MiB (phase A)
  unsigned short* wb_fx1 = (unsigned short*)(ws + 0);         // 1 MiB (after posffn2)
  unsigned short* wb_fx2 = (unsigned short*)(ws + 1 * MiB);
  unsigned short* wb_f1 = (unsigned short*)(ws + 2 * MiB);
  unsigned short* wb_f2 = (unsigned short*)(ws + 3 * MiB);
  float2* wfhT = (float2*)(ws + 12 * MiB);                    // 16.01 MiB
  unsigned short* xb = (unsigned short*)(ws + 12 * MiB);      // 16 MiB (after conv)
  float* lnzT = (float*)(ws + 29 * MiB);                      // 32 MiB
  float* yb = (float*)(ws + 29 * MiB);                        // 32 MiB (after conv)
  float* convT = (float*)(ws + 61 * MiB);                     // 32 MiB
  unsigned short* H = (unsigned short*)(ws + 61 * MiB);       // 32 MiB (after fuse)
  float* t1 = (float*)(ws + 93 * MiB);                        // 32 MiB
  unsigned short* ylnb = (unsigned short*)(ws + 93 * MiB);    // 16 MiB (after gemm2)

  // filter path
  k_posffn1<<<256, 256, 0, stream>>>(pos, pos_w1, pos_b1, p1);
  k_posffn2<<<256, 256, 0, stream>>>(p1, pos_w2, pos_b2, a, whT);
  k_filter_fft<<<256, 512, 0, stream>>>(whT, wfhT);
  // weight converts (p1 region now dead)
  k_cvt_bf16<<<256, 256, 0, stream>>>(ffnx_w1, wb_fx1, (1024 * 512) / 4);
  k_cvt_bf16<<<256, 256, 0, stream>>>(ffnx_w2, wb_fx2, (512 * 1024) / 4);
  k_cvt_bf16<<<256, 256, 0, stream>>>(ffn_w1, wb_f1, (1024 * 512) / 4);
  k_cvt_bf16<<<256, 256, 0, stream>>>(ffn_w2, wb_f2, (512 * 1024) / 4);
  // data path: LN+transpose -> FFT conv -> transpose back + LN
  k_ln_tr_z<<<dim3(256, 4), 256, 0, stream>>>(z, ln_g, ln_b, lnzT);
  k_conv_fft<<<dim3(256, 4), 512, 0, stream>>>(lnzT, wfhT, convT);
  k_fuse_t1<<<dim3(256, 4), 256, 0, stream>>>(convT, z, ln_g, ln_b, t1);
  // FFN chain (bf16 MFMA)
  k_cvt_bf16<<<4096, 256, 0, stream>>>(x, xb, (MSEQ * 512) / 4);
  k_gemm<0><<<dim3(8, 128), 256, 0, stream>>>(xb, wb_fx1, ffnx_b1, nullptr, H, MSEQ, 1024, 512);
  k_gemm<1><<<dim3(4, 128), 256, 0, stream>>>(H, wb_fx2, ffnx_b2, t1, yb, MSEQ, 512, 1024);
  k_lny<<<4096, 256, 0, stream>>>(yb, ln_g, ln_b, ylnb);
  k_gemm<0><<<dim3(8, 128), 256, 0, stream>>>(ylnb, wb_f1, ffn_b1, nullptr, H, MSEQ, 1024, 512);
  k_gemm<2><<<dim3(4, 128), 256, 0, stream>>>(H, wb_f2, ffn_b2, yb, outp, MSEQ, 512, 1024);
}

// Round 5
// 473.324 us; speedup vs baseline: 1.2556x; 1.0571x over previous
//
#include <hip/hip_runtime.h>
#include <hip/hip_bf16.h>
#include <stdint.h>

// ---------------------------------------------------------------------------
// HyenaBaseBlock: LN -> FFT causal conv (n=8192) -> +z -> LN -> *FFN(x) -> LN
// -> FFN -> +residual.  f32 fused-radix-2^2 FFT in LDS (interleaved complex,
// register twiddles), bf16 MFMA GEMMs for the FFNs.
// ---------------------------------------------------------------------------

typedef __attribute__((ext_vector_type(8))) short bf16x8;
typedef __attribute__((ext_vector_type(4))) float f32x4;
typedef const __attribute__((address_space(1))) void* as1cv;
typedef __attribute__((address_space(3))) void* as3v;

#define DEVI __device__ __forceinline__

#define B_ 4
#define L_ 4096
#define D_ 512
#define MSEQ 16384   // B_*L_

// padded LDS complex address: word offset = 2*PADW(c); spreads stride patterns
#define PADW(e) ((e) + ((e) >> 4) + ((e) >> 7))
#define CWORDS 17532        // 2*PADW(8191)+2

DEVI void gld_lds16(const void* g, void* l) {
  __builtin_amdgcn_global_load_lds((as1cv)(uintptr_t)g, (as3v)(uintptr_t)l, 16, 0, 0);
}

DEVI unsigned short to_bf16_bits(float v) {
  __hip_bfloat16 h = __float2bfloat16(v);
  return *reinterpret_cast<unsigned short*>(&h);
}

DEVI float2* cptr(float* sb, int c) {
  return (float2*)(sb + 2 * PADW(c));
}

// ---- fused forward DIF pair (S, S-1); ZH: top half (c,d inputs) are zero ---
template <int S, bool ZH>
DEVI void fwd_pair(float* sb, const int tid) {
  constexpr int h = 1 << (S - 1);
  const int jb = tid & (h - 1);
  float sn, cs;
  __sincosf((float)jb * (-3.14159265358979323846f / (float)(1 << S)), &sn, &cs);
  const float2 wb = make_float2(cs, sn);
#pragma unroll
  for (int i = 0; i < 4; ++i) {
    const int g = tid + 512 * i;
    int j;
    float2 w1;
    if constexpr (S == 12) {
      j = g & (h - 1);
      constexpr float rc[4] = {1.f, 0.92387953f, 0.70710678f, 0.38268343f};
      constexpr float rs[4] = {0.f, -0.38268343f, -0.70710678f, -0.92387953f};
      w1 = make_float2(wb.x * rc[i] - wb.y * rs[i], wb.x * rs[i] + wb.y * rc[i]);
    } else {
      j = jb;
      w1 = wb;
    }
    const int ia = ((g >> (S - 1)) << (S + 1)) + j;
    float2* Pa = cptr(sb, ia);
    float2* Pb = cptr(sb, ia + h);
    float2* Pc = cptr(sb, ia + 2 * h);
    float2* Pd = cptr(sb, ia + 3 * h);
    const float2 a = *Pa, b = *Pb;
    const float2 w3 = make_float2(w1.x * w1.x - w1.y * w1.y, 2.f * w1.x * w1.y);
    float2 t0, t1, t2, t3;
    if constexpr (ZH) {
      t0 = a;
      t1 = make_float2(a.x * w1.x - a.y * w1.y, a.x * w1.y + a.y * w1.x);
      t2 = b;
      t3 = make_float2(b.x * w1.y + b.y * w1.x, b.y * w1.y - b.x * w1.x);  // b*(-i w1)
    } else {
      const float2 c = *Pc, d = *Pd;
      t0 = make_float2(a.x + c.x, a.y + c.y);
      const float ur = a.x - c.x, ui = a.y - c.y;
      t1 = make_float2(ur * w1.x - ui * w1.y, ur * w1.y + ui * w1.x);
      t2 = make_float2(b.x + d.x, b.y + d.y);
      const float vr = b.x - d.x, vi = b.y - d.y;
      t3 = make_float2(vr * w1.y + vi * w1.x, vi * w1.y - vr * w1.x);       // (b-d)*(-i w1)
    }
    *Pa = make_float2(t0.x + t2.x, t0.y + t2.y);
    float xr = t0.x - t2.x, xi = t0.y - t2.y;
    *Pb = make_float2(xr * w3.x - xi * w3.y, xr * w3.y + xi * w3.x);
    *Pc = make_float2(t1.x + t3.x, t1.y + t3.y);
    xr = t1.x - t3.x; xi = t1.y - t3.y;
    *Pd = make_float2(xr * w3.x - xi * w3.y, xr * w3.y + xi * w3.x);
  }
  __syncthreads();
}

// ---- fused inverse DIT pair (S, S+1); DH: drop stores to upper half --------
template <int S, bool DH>
DEVI void inv_pair(float* sb, const int tid) {
  constexpr int h = 1 << S;
  const int jb = tid & (h - 1);
  float sn, cs;
  __sincosf((float)jb * (3.14159265358979323846f / (float)(1 << (S + 1))), &sn, &cs);
  const float2 wb = make_float2(cs, sn);
#pragma unroll
  for (int i = 0; i < 4; ++i) {
    const int g = tid + 512 * i;
    int j;
    float2 w2;
    if constexpr (S == 11) {
      j = g & (h - 1);
      constexpr float rc[4] = {1.f, 0.92387953f, 0.70710678f, 0.38268343f};
      constexpr float rs[4] = {0.f, 0.38268343f, 0.70710678f, 0.92387953f};
      w2 = make_float2(wb.x * rc[i] - wb.y * rs[i], wb.x * rs[i] + wb.y * rc[i]);
    } else {
      j = jb;
      w2 = wb;
    }
    const int ia = ((g >> S) << (S + 2)) + j;
    float2* Pa = cptr(sb, ia);
    float2* Pb = cptr(sb, ia + h);
    float2* Pc = cptr(sb, ia + 2 * h);
    float2* Pd = cptr(sb, ia + 3 * h);
    const float2 a = *Pa, b = *Pb, c = *Pc, d = *Pd;
    const float2 w1 = make_float2(w2.x * w2.x - w2.y * w2.y, 2.f * w2.x * w2.y);
    // stage S
    const float2 vb = make_float2(b.x * w1.x - b.y * w1.y, b.x * w1.y + b.y * w1.x);
    const float2 t0 = make_float2(a.x + vb.x, a.y + vb.y);
    const float2 t1 = make_float2(a.x - vb.x, a.y - vb.y);
    const float2 vd = make_float2(d.x * w1.x - d.y * w1.y, d.x * w1.y + d.y * w1.x);
    const float2 t2 = make_float2(c.x + vd.x, c.y + vd.y);
    const float2 t3 = make_float2(c.x - vd.x, c.y - vd.y);
    // stage S+1
    const float2 vc = make_float2(t2.x * w2.x - t2.y * w2.y, t2.x * w2.y + t2.y * w2.x);
    *Pa = make_float2(t0.x + vc.x, t0.y + vc.y);
    if (!DH) *Pc = make_float2(t0.x - vc.x, t0.y - vc.y);
    const float2 vd2 = make_float2(-t3.x * w2.y - t3.y * w2.x, t3.x * w2.x - t3.y * w2.y); // t3*(i w2)
    *Pb = make_float2(t1.x + vd2.x, t1.y + vd2.y);
    if (!DH) *Pd = make_float2(t1.x - vd2.x, t1.y - vd2.y);
  }
  __syncthreads();
}

// ---- single trivial stage 0 (twiddle = 1), shared by fwd tail / inv head ---
DEVI void fft_stage0(float* sb, const int tid) {
#pragma unroll
  for (int i = 0; i < 8; ++i) {
    const int p = tid + 512 * i;
    float2* P0 = cptr(sb, 2 * p);
    float2* P1 = cptr(sb, 2 * p + 1);
    const float2 u = *P0, v = *P1;
    *P0 = make_float2(u.x + v.x, u.y + v.y);
    *P1 = make_float2(u.x - v.x, u.y - v.y);
  }
  __syncthreads();
}

DEVI void fft_fwd_all(float* sb, const int tid) {
  fwd_pair<12, true>(sb, tid);
  fwd_pair<10, false>(sb, tid);
  fwd_pair<8, false>(sb, tid);
  fwd_pair<6, false>(sb, tid);
  fwd_pair<4, false>(sb, tid);
  fwd_pair<2, false>(sb, tid);
  fft_stage0(sb, tid);
}

DEVI void fft_inv_all(float* sb, const int tid) {
  fft_stage0(sb, tid);
  inv_pair<1, false>(sb, tid);
  inv_pair<3, false>(sb, tid);
  inv_pair<5, false>(sb, tid);
  inv_pair<7, false>(sb, tid);
  inv_pair<9, false>(sb, tid);
  inv_pair<11, true>(sb, tid);   // only t<4096 outputs needed
}

// ---------------- pos FFN layer 1: p1 = silu(pos @ w1^T + b1)  [4096,256] ---
__global__ __launch_bounds__(256) void k_posffn1(const float* __restrict__ pos,
                                                 const float* __restrict__ w1,
                                                 const float* __restrict__ b1,
                                                 float* __restrict__ p1) {
  __shared__ float sp[16 * 128];
  const int tid = threadIdx.x;
  const int m0 = blockIdx.x * 16;
  const float4* src = (const float4*)(pos + (size_t)m0 * 128);
  float4* dst = (float4*)sp;
  for (int i = tid; i < 512; i += 256) dst[i] = src[i];
  __syncthreads();
  const int n = tid;
  float acc[16];
  const float bias = b1[n];
#pragma unroll
  for (int m = 0; m < 16; ++m) acc[m] = bias;
  const float* w = w1 + (size_t)n * 128;
  for (int k = 0; k < 128; ++k) {
    const float wv = w[k];
#pragma unroll
    for (int m = 0; m < 16; ++m) acc[m] = fmaf(sp[m * 128 + k], wv, acc[m]);
  }
#pragma unroll
  for (int m = 0; m < 16; ++m) {
    const float v = acc[m];
    p1[(size_t)(m0 + m) * 256 + n] = v / (1.f + __expf(-v));
  }
}

// ---- pos FFN layer 2 + window, write transposed whT[d][t] = win[t]*h[t][d] -
__global__ __launch_bounds__(256) void k_posffn2(const float* __restrict__ p1,
                                                 const float* __restrict__ w2,
                                                 const float* __restrict__ b2,
                                                 const float* __restrict__ a,
                                                 float* __restrict__ whT) {
  __shared__ float sp[16 * 256];
  __shared__ float so[16 * 512];
  const int tid = threadIdx.x;
  const int t0 = blockIdx.x * 16;
  const float4* src = (const float4*)(p1 + (size_t)t0 * 256);
  float4* dst = (float4*)sp;
  for (int i = tid; i < 1024; i += 256) dst[i] = src[i];
  __syncthreads();
  for (int half = 0; half < 2; ++half) {
    const int d = tid + half * 256;
    float acc[16];
    const float bias = b2[d];
#pragma unroll
    for (int m = 0; m < 16; ++m) acc[m] = bias;
    const float* w = w2 + (size_t)d * 256;
    for (int k = 0; k < 256; ++k) {
      const float wv = w[k];
#pragma unroll
      for (int m = 0; m < 16; ++m) acc[m] = fmaf(sp[m * 256 + k], wv, acc[m]);
    }
#pragma unroll
    for (int m = 0; m < 16; ++m) so[m * 512 + d] = acc[m];
  }
  __syncthreads();
  const float expa = __expf(a[0]);
  for (int half = 0; half < 2; ++half) {
    const int d = tid + half * 256;
    float out[16];
#pragma unroll
    for (int m = 0; m < 16; ++m) {
      const float win = __expf(-(float)(t0 + m) * expa);
      out[m] = so[m * 512 + d] * win;
    }
    float4* o4 = (float4*)(whT + (size_t)d * 4096 + t0);
    o4[0] = make_float4(out[0], out[1], out[2], out[3]);
    o4[1] = make_float4(out[4], out[5], out[6], out[7]);
    o4[2] = make_float4(out[8], out[9], out[10], out[11]);
    o4[3] = make_float4(out[12], out[13], out[14], out[15]);
  }
}

// -------- filter FFT: 2 channels packed per block; store W/8192, natural k --
__global__ __launch_bounds__(512) void k_filter_fft(const float* __restrict__ whT,
                                                    float2* __restrict__ wfhT) {
  __shared__ float sb[CWORDS];
  const int tid = threadIdx.x;
  const int d0 = blockIdx.x * 2, d1 = d0 + 1;
  const float* h0 = whT + (size_t)d0 * 4096;
  const float* h1 = whT + (size_t)d1 * 4096;
  for (int t4 = tid; t4 < 1024; t4 += 512) {
    const float4 v0 = ((const float4*)h0)[t4];
    const float4 v1 = ((const float4*)h1)[t4];
    *cptr(sb, 4 * t4 + 0) = make_float2(v0.x, v1.x);
    *cptr(sb, 4 * t4 + 1) = make_float2(v0.y, v1.y);
    *cptr(sb, 4 * t4 + 2) = make_float2(v0.z, v1.z);
    *cptr(sb, 4 * t4 + 3) = make_float2(v0.w, v1.w);
  }
  __syncthreads();
  fft_fwd_all(sb, tid);
  const float sc = 1.0f / 8192.0f;
  const int lane = tid & 63;
  const int rl = __brev(lane) >> 26;
  const int qb = tid & ~63;
  for (int it = 0; it < 8; ++it) {
    const int q = it * 512 + qb + rl;
    if (q == 0) {
      // bin 0 at pos 0; bin 4096 at bitrev pos 1 (both real-valued)
      const float2 x0 = *cptr(sb, 0);
      const float2 x1 = *cptr(sb, 1);
      wfhT[(size_t)d0 * 4097 + 0]    = make_float2(x0.x * sc, 0.f);
      wfhT[(size_t)d1 * 4097 + 0]    = make_float2(x0.y * sc, 0.f);
      wfhT[(size_t)d0 * 4097 + 4096] = make_float2(x1.x * sc, 0.f);
      wfhT[(size_t)d1 * 4097 + 4096] = make_float2(x1.y * sc, 0.f);
    } else {
      const int kk = __brev(q) >> 19;
      const int mm = __brev(8192 - q) >> 19;
      const float2 Xk = *cptr(sb, kk);
      const float2 Xm = *cptr(sb, mm);
      wfhT[(size_t)d0 * 4097 + q] = make_float2(0.5f * (Xk.x + Xm.x) * sc, 0.5f * (Xk.y - Xm.y) * sc);
      wfhT[(size_t)d1 * 4097 + q] = make_float2(0.5f * (Xk.y + Xm.y) * sc, 0.5f * (Xm.x - Xk.x) * sc);
    }
  }
}

// ---------------- LN(z) + transpose to lnzT[b][d][t] ------------------------
__global__ __launch_bounds__(256) void k_ln_tr_z(const float* __restrict__ z,
                                                 const float* __restrict__ g,
                                                 const float* __restrict__ be,
                                                 float* __restrict__ lnzT) {
  __shared__ float sd[16 * 516];
  __shared__ float smu[16], srs[16];
  const int tid = threadIdx.x;
  const int b = blockIdx.y;
  const int t0 = blockIdx.x * 16;
  for (int i = tid; i < 16 * 128; i += 256) {
    const int row = i >> 7, c4 = i & 127;
    const float4 v = *(const float4*)(z + ((size_t)b * 4096 + t0 + row) * 512 + c4 * 4);
    *(float4*)(&sd[row * 516 + c4 * 4]) = v;
  }
  __syncthreads();
  const int r = tid >> 4, s = tid & 15;
  float sum = 0.f, sq = 0.f;
#pragma unroll
  for (int i = 0; i < 8; ++i) {
    const int c4 = s + 16 * i;
    const float4 v = *(const float4*)(&sd[r * 516 + c4 * 4]);
    sum += v.x + v.y + v.z + v.w;
    sq += v.x * v.x + v.y * v.y + v.z * v.z + v.w * v.w;
  }
#pragma unroll
  for (int off = 1; off < 16; off <<= 1) {
    sum += __shfl_xor(sum, off);
    sq += __shfl_xor(sq, off);
  }
  if (s == 0) {
    const float mu = sum * (1.f / 512.f);
    const float var = sq * (1.f / 512.f) - mu * mu;
    smu[r] = mu;
    srs[r] = rsqrtf(var + 1e-5f);
  }
  __syncthreads();
  for (int pass = 0; pass < 8; ++pass) {
    const int d = pass * 64 + (tid >> 2);
    const int q = tid & 3;
    const float gg = g[d], bb = be[d];
    float4 o;
    o.x = (sd[(q * 4 + 0) * 516 + d] - smu[q * 4 + 0]) * srs[q * 4 + 0] * gg + bb;
    o.y = (sd[(q * 4 + 1) * 516 + d] - smu[q * 4 + 1]) * srs[q * 4 + 1] * gg + bb;
    o.z = (sd[(q * 4 + 2) * 516 + d] - smu[q * 4 + 2]) * srs[q * 4 + 2] * gg + bb;
    o.w = (sd[(q * 4 + 3) * 516 + d] - smu[q * 4 + 3]) * srs[q * 4 + 3] * gg + bb;
    *(float4*)(lnzT + ((size_t)b * 512 + d) * 4096 + t0 + q * 4) = o;
  }
}

// ------- fused conv: fwdFFT(2ch packed) * W -> invFFT -> convT[b][d][t] -----
__global__ __launch_bounds__(512) void k_conv_fft(const float* __restrict__ lnzT,
                                                  const float2* __restrict__ wfhT,
                                                  float* __restrict__ convT) {
  __shared__ float sb[CWORDS];
  const int tid = threadIdx.x;
  const int d0 = blockIdx.x * 2, d1 = d0 + 1;
  const int b = blockIdx.y;
  const float* z0 = lnzT + ((size_t)b * 512 + d0) * 4096;
  const float* z1 = lnzT + ((size_t)b * 512 + d1) * 4096;
  for (int t4 = tid; t4 < 1024; t4 += 512) {
    const float4 v0 = ((const float4*)z0)[t4];
    const float4 v1 = ((const float4*)z1)[t4];
    *cptr(sb, 4 * t4 + 0) = make_float2(v0.x, v1.x);
    *cptr(sb, 4 * t4 + 1) = make_float2(v0.y, v1.y);
    *cptr(sb, 4 * t4 + 2) = make_float2(v0.z, v1.z);
    *cptr(sb, 4 * t4 + 3) = make_float2(v0.w, v1.w);
  }
  __syncthreads();
  fft_fwd_all(sb, tid);   // first pass treats top half as zero
  const float2* W0 = wfhT + (size_t)d0 * 4097;
  const float2* W1 = wfhT + (size_t)d1 * 4097;
  const int lane = tid & 63;
  const int rl = __brev(lane) >> 26;
  const int qb = tid & ~63;
  for (int it = 0; it < 8; ++it) {
    const int q = it * 512 + qb + rl;
    if (q == 0) {
      float2* P0 = cptr(sb, 0);
      float2* P1 = cptr(sb, 1);
      float2 x0 = *P0, x1 = *P1;
      x0.x *= W0[0].x;    x0.y *= W1[0].x;
      x1.x *= W0[4096].x; x1.y *= W1[4096].x;
      *P0 = x0; *P1 = x1;
    } else {
      const int kk = __brev(q) >> 19;
      const int mm = __brev(8192 - q) >> 19;
      float2* Pk = cptr(sb, kk);
      float2* Pm = cptr(sb, mm);
      const float2 Xk = *Pk, Xm = *Pm;
      const float f1r = 0.5f * (Xk.x + Xm.x), f1i = 0.5f * (Xk.y - Xm.y);
      const float f2r = 0.5f * (Xk.y + Xm.y), f2i = 0.5f * (Xm.x - Xk.x);
      const float2 w1 = W0[q], w2 = W1[q];
      const float g1r = w1.x * f1r - w1.y * f1i, g1i = w1.x * f1i + w1.y * f1r;
      const float g2r = w2.x * f2r - w2.y * f2i, g2i = w2.x * f2i + w2.y * f2r;
      *Pk = make_float2(g1r - g2i, g1i + g2r);
      *Pm = make_float2(g1r + g2i, g2r - g1i);
    }
  }
  __syncthreads();
  fft_inv_all(sb, tid);
  float* o0 = convT + ((size_t)b * 512 + d0) * 4096;
  float* o1 = convT + ((size_t)b * 512 + d1) * 4096;
  for (int t4 = tid; t4 < 1024; t4 += 512) {
    const float2 c0 = *cptr(sb, 4 * t4 + 0);
    const float2 c1 = *cptr(sb, 4 * t4 + 1);
    const float2 c2 = *cptr(sb, 4 * t4 + 2);
    const float2 c3 = *cptr(sb, 4 * t4 + 3);
    ((float4*)o0)[t4] = make_float4(c0.x, c1.x, c2.x, c3.x);
    ((float4*)o1)[t4] = make_float4(c0.y, c1.y, c2.y, c3.y);
  }
}

// ------ fuse: cwhz = convT^T + z ; t1 = LN(cwhz) -> [b][t][d] rows ----------
__global__ __launch_bounds__(256) void k_fuse_t1(const float* __restrict__ convT,
                                                 const float* __restrict__ z,
                                                 const float* __restrict__ g,
                                                 const float* __restrict__ be,
                                                 float* __restrict__ t1) {
  __shared__ float sd[16 * 516];
  __shared__ float smu[16], srs[16];
  const int tid = threadIdx.x;
  const int b = blockIdx.y;
  const int t0 = blockIdx.x * 16;
  for (int pass = 0; pass < 8; ++pass) {
    const int d = pass * 64 + (tid >> 2);
    const int q = tid & 3;
    const float4 v = *(const float4*)(convT + ((size_t)b * 512 + d) * 4096 + t0 + q * 4);
    sd[(q * 4 + 0) * 516 + d] = v.x;
    sd[(q * 4 + 1) * 516 + d] = v.y;
    sd[(q * 4 + 2) * 516 + d] = v.z;
    sd[(q * 4 + 3) * 516 + d] = v.w;
  }
  __syncthreads();
  const int r = tid >> 4, s = tid & 15;
  const float* zr = z + ((size_t)b * 4096 + t0 + r) * 512;
  float sum = 0.f, sq = 0.f;
#pragma unroll
  for (int i = 0; i < 8; ++i) {
    const int c4 = s + 16 * i;
    const float4 zv = *(const float4*)(zr + c4 * 4);
    float* p = &sd[r * 516 + c4 * 4];
    const float v0 = p[0] + zv.x, v1 = p[1] + zv.y, v2 = p[2] + zv.z, v3 = p[3] + zv.w;
    p[0] = v0; p[1] = v1; p[2] = v2; p[3] = v3;
    sum += v0 + v1 + v2 + v3;
    sq += v0 * v0 + v1 * v1 + v2 * v2 + v3 * v3;
  }
#pragma unroll
  for (int off = 1; off < 16; off <<= 1) {
    sum += __shfl_xor(sum, off);
    sq += __shfl_xor(sq, off);
  }
  if (s == 0) {
    const float mu = sum * (1.f / 512.f);
    const float var = sq * (1.f / 512.f) - mu * mu;
    smu[r] = mu;
    srs[r] = rsqrtf(var + 1e-5f);
  }
  __syncthreads();
  for (int i = tid; i < 16 * 128; i += 256) {
    const int row = i >> 7, c4 = i & 127;
    const float mu = smu[row], rs = srs[row];
    const float4 gv = *(const float4*)(g + c4 * 4);
    const float4 bv = *(const float4*)(be + c4 * 4);
    const float* p = &sd[row * 516 + c4 * 4];
    float4 o;
    o.x = (p[0] - mu) * rs * gv.x + bv.x;
    o.y = (p[1] - mu) * rs * gv.y + bv.y;
    o.z = (p[2] - mu) * rs * gv.z + bv.z;
    o.w = (p[3] - mu) * rs * gv.w + bv.w;
    *(float4*)(t1 + ((size_t)b * 4096 + t0 + row) * 512 + c4 * 4) = o;
  }
}

// ---------------- f32 -> bf16 convert (grid-stride, float4-wise) ------------
__global__ __launch_bounds__(256) void k_cvt_bf16(const float* __restrict__ in,
                                                  unsigned short* __restrict__ out,
                                                  int n4) {
  const int stride = gridDim.x * 256;
  for (int i = blockIdx.x * 256 + threadIdx.x; i < n4; i += stride) {
    const float4 v = ((const float4*)in)[i];
    ushort4 o;
    o.x = to_bf16_bits(v.x);
    o.y = to_bf16_bits(v.y);
    o.z = to_bf16_bits(v.z);
    o.w = to_bf16_bits(v.w);
    ((ushort4*)out)[i] = o;
  }
}

// ---------------- LN(y) rows -> bf16 ----------------------------------------
__global__ __launch_bounds__(256) void k_lny(const float* __restrict__ y,
                                             const float* __restrict__ g,
                                             const float* __restrict__ be,
                                             unsigned short* __restrict__ out) {
  const int tid = threadIdx.x;
  const int lane = tid & 63, w = tid >> 6;
  const size_t row = (size_t)blockIdx.x * 4 + w;
  const float4* yr = (const float4*)(y + row * 512);
  const float4 v0 = yr[lane], v1 = yr[lane + 64];
  float sum = v0.x + v0.y + v0.z + v0.w + v1.x + v1.y + v1.z + v1.w;
  float sq = v0.x * v0.x + v0.y * v0.y + v0.z * v0.z + v0.w * v0.w +
             v1.x * v1.x + v1.y * v1.y + v1.z * v1.z + v1.w * v1.w;
#pragma unroll
  for (int off = 1; off < 64; off <<= 1) {
    sum += __shfl_xor(sum, off);
    sq += __shfl_xor(sq, off);
  }
  const float mu = sum * (1.f / 512.f);
  const float var = sq * (1.f / 512.f) - mu * mu;
  const float rs = rsqrtf(var + 1e-5f);
  const float4* g4 = (const float4*)g;
  const float4* b4 = (const float4*)be;
  const float4 g0 = g4[lane], g1 = g4[lane + 64];
  const float4 bb0 = b4[lane], bb1 = b4[lane + 64];
  ushort4 o0, o1;
  o0.x = to_bf16_bits((v0.x - mu) * rs * g0.x + bb0.x);
  o0.y = to_bf16_bits((v0.y - mu) * rs * g0.y + bb0.y);
  o0.z = to_bf16_bits((v0.z - mu) * rs * g0.z + bb0.z);
  o0.w = to_bf16_bits((v0.w - mu) * rs * g0.w + bb0.w);
  o1.x = to_bf16_bits((v1.x - mu) * rs * g1.x + bb1.x);
  o1.y = to_bf16_bits((v1.y - mu) * rs * g1.y + bb1.y);
  o1.z = to_bf16_bits((v1.z - mu) * rs * g1.z + bb1.z);
  o1.w = to_bf16_bits((v1.w - mu) * rs * g1.w + bb1.w);
  ((ushort4*)out)[row * 128 + lane] = o0;
  ((ushort4*)out)[row * 128 + lane + 64] = o1;
}

// ---------------- bf16 MFMA GEMM: C = A[M,K] @ B[N,K]^T + epi ---------------
// EPI 0: silu(v+bias) -> bf16    EPI 1: (v+bias)*extra -> f32
// EPI 2: (v+bias)+extra -> f32
template <int EPI>
__global__ __launch_bounds__(256) void k_gemm(const unsigned short* __restrict__ A,
                                              const unsigned short* __restrict__ Bw,
                                              const float* __restrict__ bias,
                                              const float* __restrict__ extra,
                                              void* __restrict__ Cout,
                                              int M, int N, int K) {
  __shared__ unsigned short sA[128 * 32];
  __shared__ unsigned short sB[128 * 32];
  const int tid = threadIdx.x;
  const int lane = tid & 63;
  const int w = tid >> 6;
  const int wr = w >> 1, wc = w & 1;
  const int m0 = blockIdx.y * 128, n0 = blockIdx.x * 128;
  f32x4 acc[4][4];
#pragma unroll
  for (int m = 0; m < 4; ++m)
#pragma unroll
    for (int n = 0; n < 4; ++n) acc[m][n] = (f32x4){0.f, 0.f, 0.f, 0.f};

  const int c_row = lane >> 2;
  const int c_off = (lane & 3) * 16;  // byte offset within 64B row
  const int nk = K >> 5;
  const int rA = lane & 15, kq = (lane >> 4) * 8;

  for (int kt = 0; kt < nk; ++kt) {
    __syncthreads();
    const int kb = kt * 32;
#pragma unroll
    for (int i = 0; i < 2; ++i) {
      const int ch = w * 2 + i;
      const int row = ch * 16 + c_row;
      gld_lds16((const char*)(A + (size_t)(m0 + row) * K + kb) + c_off,
                (char*)sA + ch * 1024);
      gld_lds16((const char*)(Bw + (size_t)(n0 + row) * K + kb) + c_off,
                (char*)sB + ch * 1024);
    }
    __syncthreads();
    bf16x8 af[4], bfv[4];
#pragma unroll
    for (int m = 0; m < 4; ++m)
      af[m] = *(const bf16x8*)(sA + (wr * 64 + m * 16 + rA) * 32 + kq);
#pragma unroll
    for (int n = 0; n < 4; ++n)
      bfv[n] = *(const bf16x8*)(sB + (wc * 64 + n * 16 + rA) * 32 + kq);
#pragma unroll
    for (int m = 0; m < 4; ++m)
#pragma unroll
      for (int n = 0; n < 4; ++n)
        acc[m][n] = __builtin_amdgcn_mfma_f32_16x16x32_bf16(af[m], bfv[n], acc[m][n], 0, 0, 0);
  }

  const int r0 = m0 + wr * 64 + (lane >> 4) * 4;
  const int c0 = n0 + wc * 64 + rA;
#pragma unroll
  for (int n = 0; n < 4; ++n) {
    const int cc = c0 + n * 16;
    const float bv = bias[cc];
#pragma unroll
    for (int m = 0; m < 4; ++m) {
#pragma unroll
      for (int j = 0; j < 4; ++j) {
        const int rr = r0 + m * 16 + j;
        const float v = acc[m][n][j] + bv;
        if constexpr (EPI == 0) {
          const float sv = v / (1.f + __expf(-v));
          ((unsigned short*)Cout)[(size_t)rr * N + cc] = to_bf16_bits(sv);
        } else if constexpr (EPI == 1) {
          ((float*)Cout)[(size_t)rr * N + cc] = v * extra[(size_t)rr * N + cc];
        } else {
          ((float*)Cout)[(size_t)rr * N + cc] = v + extra[(size_t)rr * N + cc];
        }
      }
    }
  }
}

// ---------------------------------------------------------------------------
extern "C" void kernel_launch(void* const* d_in, const int* in_sizes, int n_in,
                              void* d_out, int out_size, void* d_ws, size_t ws_size,
                              hipStream_t stream) {
  const float* z = (const float*)d_in[0];
  const float* x = (const float*)d_in[1];
  const float* pos = (const float*)d_in[2];
  const float* pos_w1 = (const float*)d_in[3];
  const float* pos_b1 = (const float*)d_in[4];
  const float* pos_w2 = (const float*)d_in[5];
  const float* pos_b2 = (const float*)d_in[6];
  const float* a = (const float*)d_in[7];
  const float* ffn_w1 = (const float*)d_in[8];
  const float* ffn_b1 = (const float*)d_in[9];
  const float* ffn_w2 = (const float*)d_in[10];
  const float* ffn_b2 = (const float*)d_in[11];
  const float* ffnx_w1 = (const float*)d_in[12];
  const float* ffnx_b1 = (const float*)d_in[13];
  const float* ffnx_w2 = (const float*)d_in[14];
  const float* ffnx_b2 = (const float*)d_in[15];
  const float* ln_g = (const float*)d_in[16];
  const float* ln_b = (const float*)d_in[17];
  float* outp = (float*)d_out;

  char* ws = (char*)d_ws;
  const size_t MiB = 1ull << 20;
  // phase-overlapped workspace (125 MiB total)
  float* p1 = (float*)(ws + 0);                               // 4 MiB (phase A)
  float* whT = (float*)(ws + 4 * MiB);                        // 8 MiB (phase A)
  unsigned short* wb_fx1 = (unsigned short*)(ws + 0);         // 1 MiB (after posffn2)
  unsigned short* wb_fx2 = (unsigned short*)(ws + 1 * MiB);
  unsigned short* wb_f1 = (unsigned short*)(ws + 2 * MiB);
  unsigned short* wb_f2 = (unsigned short*)(ws + 3 * MiB);
  float2* wfhT = (float2*)(ws + 12 * MiB);                    // 16.01 MiB
  unsigned short* xb = (unsigned short*)(ws + 12 * MiB);      // 16 MiB (after conv)
  float* lnzT = (float*)(ws + 29 * MiB);                      // 32 MiB
  float* yb = (float*)(ws + 29 * MiB);                        // 32 MiB (after conv)
  float* convT = (float*)(ws + 61 * MiB);                     // 32 MiB
  unsigned short* H = (unsigned short*)(ws + 61 * MiB);       // 32 MiB (after fuse)
  float* t1 = (float*)(ws + 93 * MiB);                        // 32 MiB
  unsigned short* ylnb = (unsigned short*)(ws + 93 * MiB);    // 16 MiB (after gemm2)

  // filter path
  k_posffn1<<<256, 256, 0, stream>>>(pos, pos_w1, pos_b1, p1);
  k_posffn2<<<256, 256, 0, stream>>>(p1, pos_w2, pos_b2, a, whT);
  k_filter_fft<<<256, 512, 0, stream>>>(whT, wfhT);
  // weight converts (p1 region now dead)
  k_cvt_bf16<<<256, 256, 0, stream>>>(ffnx_w1, wb_fx1, (1024 * 512) / 4);
  k_cvt_bf16<<<256, 256, 0, stream>>>(ffnx_w2, wb_fx2, (512 * 1024) / 4);
  k_cvt_bf16<<<256, 256, 0, stream>>>(ffn_w1, wb_f1, (1024 * 512) / 4);
  k_cvt_bf16<<<256, 256, 0, stream>>>(ffn_w2, wb_f2, (512 * 1024) / 4);
  // data path: LN+transpose -> FFT conv -> transpose back + LN
  k_ln_tr_z<<<dim3(256, 4), 256, 0, stream>>>(z, ln_g, ln_b, lnzT);
  k_conv_fft<<<dim3(256, 4), 512, 0, stream>>>(lnzT, wfhT, convT);
  k_fuse_t1<<<dim3(256, 4), 256, 0, stream>>>(convT, z, ln_g, ln_b, t1);
  // FFN chain (bf16 MFMA)
  k_cvt_bf16<<<4096, 256, 0, stream>>>(x, xb, (MSEQ * 512) / 4);
  k_gemm<0><<<dim3(8, 128), 256, 0, stream>>>(xb, wb_fx1, ffnx_b1, nullptr, H, MSEQ, 1024, 512);
  k_gemm<1><<<dim3(4, 128), 256, 0, stream>>>(H, wb_fx2, ffnx_b2, t1, yb, MSEQ, 512, 1024);
  k_lny<<<4096, 256, 0, stream>>>(yb, ln_g, ln_b, ylnb);
  k_gemm<0><<<dim3(8, 128), 256, 0, stream>>>(ylnb, wb_f1, ffn_b1, nullptr, H, MSEQ, 1024, 512);
  k_gemm<2><<<dim3(4, 128), 256, 0, stream>>>(H, wb_f2, ffn_b2, yb, outp, MSEQ, 512, 1024);
}

// Round 8
// 443.020 us; speedup vs baseline: 1.3415x; 1.0684x over previous
//
#include <hip/hip_runtime.h>
#include <hip/hip_bf16.h>
#include <stdint.h>

// ---------------------------------------------------------------------------
// HyenaBaseBlock: LN -> FFT causal conv (n=8192) -> +z -> LN -> *FFN(x) -> LN
// -> FFN -> +residual.
// FFT: 4-step register radix-16 (3 phases/direction, natural-order spectrum),
// f32 in LDS.  FFNs: bf16 MFMA GEMMs with XCD-chunked block swizzle.
// ---------------------------------------------------------------------------

typedef __attribute__((ext_vector_type(8))) short bf16x8;
typedef __attribute__((ext_vector_type(4))) float f32x4;
typedef const __attribute__((address_space(1))) void* as1cv;
typedef __attribute__((address_space(3))) void* as3v;

#define DEVI __device__ __forceinline__

#define B_ 4
#define L_ 4096
#define D_ 512
#define MSEQ 16384   // B_*L_

DEVI void gld_lds16(const void* g, void* l) {
  __builtin_amdgcn_global_load_lds((as1cv)(uintptr_t)g, (as3v)(uintptr_t)l, 16, 0, 0);
}

DEVI unsigned short to_bf16_bits(float v) {
  __hip_bfloat16 h = __float2bfloat16(v);
  return *reinterpret_cast<unsigned short*>(&h);
}

// ------------------------- complex helpers ---------------------------------
DEVI float2 cmul(float2 a, float2 b) {
  return make_float2(a.x * b.x - a.y * b.y, a.x * b.y + a.y * b.x);
}
DEVI float2 cmulc(float2 a, float c, float s) {
  return make_float2(a.x * c - a.y * s, a.x * s + a.y * c);
}
DEVI float2 cadd(float2 a, float2 b) { return make_float2(a.x + b.x, a.y + b.y); }
DEVI float2 csub(float2 a, float2 b) { return make_float2(a.x - b.x, a.y - b.y); }

// bit-reverse-4 table: after DIF dft16, spectral k sits at slot BR4[k]
__device__ constexpr int BR4[16] = {0, 8, 4, 12, 2, 10, 6, 14, 1, 9, 5, 13, 3, 11, 7, 15};

// 16-point DIF DFT in registers, natural in -> bitrev out.
// INV=false: twiddles e^{-2pi i k/16}; INV=true: conjugate. ZH: v[8..15]=0 on entry.
template <bool INV, bool ZH>
DEVI void dft16(float2 v[16]) {
  constexpr float C16[8] = {1.f, 0.923879533f, 0.707106781f, 0.382683432f,
                            0.f, -0.382683432f, -0.707106781f, -0.923879533f};
  constexpr float S16[8] = {0.f, 0.382683432f, 0.707106781f, 0.923879533f,
                            1.f, 0.923879533f, 0.707106781f, 0.382683432f};
  constexpr float C8[4] = {1.f, 0.707106781f, 0.f, -0.707106781f};
  constexpr float S8[4] = {0.f, 0.707106781f, 1.f, 0.707106781f};
  const float SG = INV ? 1.f : -1.f;
  // stage len=8
#pragma unroll
  for (int i = 0; i < 8; ++i) {
    if (ZH) {
      v[i + 8] = cmulc(v[i], C16[i], SG * S16[i]);
      // v[i] unchanged
    } else {
      const float2 u = v[i], w = v[i + 8];
      v[i] = cadd(u, w);
      v[i + 8] = cmulc(csub(u, w), C16[i], SG * S16[i]);
    }
  }
  // stage len=4
#pragma unroll
  for (int h = 0; h < 16; h += 8)
#pragma unroll
    for (int i = 0; i < 4; ++i) {
      const float2 u = v[h + i], w = v[h + i + 4];
      v[h + i] = cadd(u, w);
      v[h + i + 4] = cmulc(csub(u, w), C8[i], SG * S8[i]);
    }
  // stage len=2 (twiddles 1, -+i)
#pragma unroll
  for (int h = 0; h < 16; h += 4) {
    float2 u = v[h], w = v[h + 2];
    v[h] = cadd(u, w);
    v[h + 2] = csub(u, w);
    u = v[h + 1]; w = v[h + 3];
    v[h + 1] = cadd(u, w);
    const float2 d = csub(u, w);
    v[h + 3] = INV ? make_float2(-d.y, d.x) : make_float2(d.y, -d.x);
  }
  // stage len=1
#pragma unroll
  for (int h = 0; h < 16; h += 2) {
    const float2 u = v[h], w = v[h + 1];
    v[h] = cadd(u, w);
    v[h + 1] = csub(u, w);
  }
}

// LDS layouts (single float2 buffer, phase-aliased):
#define L1IDX(k1, t) ((k1) * 516 + (t))           // [16][512] pad->516
#define L2IDX(k1, k2, s) ((k1) * 529 + (k2) * 33 + (s))  // [16][16][32] pad
#define PADQ(q) ((q) + ((q) >> 5))                 // natural-q, max 8446
#define SBSZ 8462

// ---- forward phase 1: load a[t+512r] (r<8; top half zero), dft16, twiddle,
// store L1[k1][t] --
template <bool INV>
DEVI void phase1_store(float2* SB, float2 v[16], int t) {
  const float SG = INV ? 1.f : -1.f;
  float sn, cs;
  __sincosf(SG * 7.6699039394282e-4f * (float)t, &sn, &cs);  // 2*pi/8192 * t
  const float2 base = make_float2(cs, sn);
  float2 tw = make_float2(1.f, 0.f);
#pragma unroll
  for (int k1 = 0; k1 < 16; ++k1) {
    if (k1) tw = cmul(tw, base);
    SB[L1IDX(k1, t)] = cmul(v[BR4[k1]], tw);
  }
}

// ---- phase 2: 16-pt over r2 (t = s+32 r2), twiddle W512^{s k2}, store L2 ---
template <bool INV>
DEVI void phase2(float2* SB, int tid) {
  const int k1 = tid >> 5, s = tid & 31;
  float2 y[16];
#pragma unroll
  for (int r2 = 0; r2 < 16; ++r2) y[r2] = SB[L1IDX(k1, s + 32 * r2)];
  __syncthreads();
  dft16<INV, false>(y);
  const float SG = INV ? 1.f : -1.f;
  float sn, cs;
  __sincosf(SG * 1.2271846303085e-2f * (float)s, &sn, &cs);  // 2*pi/512 * s
  const float2 base = make_float2(cs, sn);
  float2 tw = make_float2(1.f, 0.f);
#pragma unroll
  for (int k2 = 0; k2 < 16; ++k2) {
    if (k2) tw = cmul(tw, base);
    SB[L2IDX(k1, k2, s)] = cmul(y[BR4[k2]], tw);
  }
  __syncthreads();
}

// ---- phase 3 fwd: radix-2 fold over s=v+16w, *W32^{v s1}, 16-pt over v,
// scatter natural q = k1+16k2+256s1+512s2 --
template <bool INV>
DEVI void phase3_fwd(float2* SB, int tid) {
  constexpr float C32[16] = {1.f, 0.980785280f, 0.923879533f, 0.831469612f,
                             0.707106781f, 0.555570233f, 0.382683432f, 0.195090322f,
                             0.f, -0.195090322f, -0.382683432f, -0.555570233f,
                             -0.707106781f, -0.831469612f, -0.923879533f, -0.980785280f};
  constexpr float S32[16] = {0.f, 0.195090322f, 0.382683432f, 0.555570233f,
                             0.707106781f, 0.831469612f, 0.923879533f, 0.980785280f,
                             1.f, 0.980785280f, 0.923879533f, 0.831469612f,
                             0.707106781f, 0.555570233f, 0.382683432f, 0.195090322f};
  const int k2 = tid & 15, s1 = (tid >> 4) & 1, k1 = tid >> 5;
  const float SG = INV ? 1.f : -1.f;
  float2 Z[16];
#pragma unroll
  for (int v = 0; v < 16; ++v) {
    const float2 A = SB[L2IDX(k1, k2, v)];
    const float2 Bv = SB[L2IDX(k1, k2, v + 16)];
    Z[v] = s1 ? csub(A, Bv) : cadd(A, Bv);
  }
  if (s1) {
#pragma unroll
    for (int v = 1; v < 16; ++v) Z[v] = cmulc(Z[v], C32[v], SG * S32[v]);
  }
  __syncthreads();
  dft16<INV, false>(Z);
  const int qb = k1 + 16 * k2 + 256 * s1;
#pragma unroll
  for (int s2 = 0; s2 < 16; ++s2) SB[PADQ(qb + 512 * s2)] = Z[BR4[s2]];
  __syncthreads();
}

// ---- phase 3 inverse: same fold/DFT; emit x[n], n = m1+16m2+256s1+512s2,
// keep s2<8 (n<4096), write global --
DEVI void phase3_inv_store(float2* SB, int tid, float* __restrict__ o0,
                           float* __restrict__ o1) {
  constexpr float C32[16] = {1.f, 0.980785280f, 0.923879533f, 0.831469612f,
                             0.707106781f, 0.555570233f, 0.382683432f, 0.195090322f,
                             0.f, -0.195090322f, -0.382683432f, -0.555570233f,
                             -0.707106781f, -0.831469612f, -0.923879533f, -0.980785280f};
  constexpr float S32[16] = {0.f, 0.195090322f, 0.382683432f, 0.555570233f,
                             0.707106781f, 0.831469612f, 0.923879533f, 0.980785280f,
                             1.f, 0.980785280f, 0.923879533f, 0.831469612f,
                             0.707106781f, 0.555570233f, 0.382683432f, 0.195090322f};
  const int m1 = tid & 15, m2 = (tid >> 4) & 15, s1 = tid >> 8;
  float2 Z[16];
#pragma unroll
  for (int v = 0; v < 16; ++v) {
    const float2 A = SB[L2IDX(m1, m2, v)];
    const float2 Bv = SB[L2IDX(m1, m2, v + 16)];
    Z[v] = s1 ? csub(A, Bv) : cadd(A, Bv);
  }
  if (s1) {
#pragma unroll
    for (int v = 1; v < 16; ++v) Z[v] = cmulc(Z[v], C32[v], S32[v]);  // conj: +s
  }
  dft16<true, false>(Z);
  const int nb = m1 + 16 * m2 + 256 * s1;
#pragma unroll
  for (int s2 = 0; s2 < 8; ++s2) {
    const int n = nb + 512 * s2;
    const float2 r = Z[BR4[s2]];
    o0[n] = r.x;
    o1[n] = r.y;
  }
}

// -------- filter FFT: 2 channels packed; store W/8192 natural-k ------------
__global__ __launch_bounds__(512, 4) void k_filter_fft(const float* __restrict__ whT,
                                                       float2* __restrict__ wfhT) {
  __shared__ float2 SB[SBSZ];
  const int tid = threadIdx.x;
  const int d0 = blockIdx.x * 2, d1 = d0 + 1;
  const float* h0 = whT + (size_t)d0 * 4096;
  const float* h1 = whT + (size_t)d1 * 4096;
  float2 v[16];
#pragma unroll
  for (int r = 0; r < 8; ++r) v[r] = make_float2(h0[tid + 512 * r], h1[tid + 512 * r]);
  dft16<false, true>(v);
  phase1_store<false>(SB, v, tid);
  __syncthreads();
  phase2<false>(SB, tid);
  phase3_fwd<false>(SB, tid);
  const float sc = 1.0f / 8192.0f;
  for (int it = 0; it < 8; ++it) {
    const int q = it * 512 + tid;
    if (q == 0) {
      const float2 x0 = SB[PADQ(0)];
      const float2 xn = SB[PADQ(4096)];
      wfhT[(size_t)d0 * 4097 + 0] = make_float2(x0.x * sc, 0.f);
      wfhT[(size_t)d1 * 4097 + 0] = make_float2(x0.y * sc, 0.f);
      wfhT[(size_t)d0 * 4097 + 4096] = make_float2(xn.x * sc, 0.f);
      wfhT[(size_t)d1 * 4097 + 4096] = make_float2(xn.y * sc, 0.f);
    } else {
      const float2 Xq = SB[PADQ(q)];
      const float2 Xm = SB[PADQ(8192 - q)];
      wfhT[(size_t)d0 * 4097 + q] =
          make_float2(0.5f * (Xq.x + Xm.x) * sc, 0.5f * (Xq.y - Xm.y) * sc);
      wfhT[(size_t)d1 * 4097 + q] =
          make_float2(0.5f * (Xq.y + Xm.y) * sc, 0.5f * (Xm.x - Xq.x) * sc);
    }
  }
}

// ------- fused conv: fwdFFT(2ch packed) * W -> invFFT -> convT[b][d][t] -----
__global__ __launch_bounds__(512, 4) void k_conv_fft(const float* __restrict__ lnzT,
                                                     const float2* __restrict__ wfhT,
                                                     float* __restrict__ convT) {
  __shared__ float2 SB[SBSZ];
  const int tid = threadIdx.x;
  const int d0 = blockIdx.x * 2, d1 = d0 + 1;
  const int b = blockIdx.y;
  const float* z0 = lnzT + ((size_t)b * 512 + d0) * 4096;
  const float* z1 = lnzT + ((size_t)b * 512 + d1) * 4096;
  // forward
  float2 v[16];
#pragma unroll
  for (int r = 0; r < 8; ++r) v[r] = make_float2(z0[tid + 512 * r], z1[tid + 512 * r]);
  dft16<false, true>(v);
  phase1_store<false>(SB, v, tid);
  __syncthreads();
  phase2<false>(SB, tid);
  phase3_fwd<false>(SB, tid);
  // pointwise multiply in natural-q order (disjoint (q, 8192-q) pairs)
  const float2* W0 = wfhT + (size_t)d0 * 4097;
  const float2* W1 = wfhT + (size_t)d1 * 4097;
  for (int it = 0; it < 8; ++it) {
    const int q = it * 512 + tid;
    if (q == 0) {
      float2 x0 = SB[PADQ(0)];
      float2 xn = SB[PADQ(4096)];
      x0.x *= W0[0].x;    x0.y *= W1[0].x;
      xn.x *= W0[4096].x; xn.y *= W1[4096].x;
      SB[PADQ(0)] = x0;
      SB[PADQ(4096)] = xn;
    } else {
      const int m = 8192 - q;
      const float2 Xq = SB[PADQ(q)];
      const float2 Xm = SB[PADQ(m)];
      const float f1r = 0.5f * (Xq.x + Xm.x), f1i = 0.5f * (Xq.y - Xm.y);
      const float f2r = 0.5f * (Xq.y + Xm.y), f2i = 0.5f * (Xm.x - Xq.x);
      const float2 w1 = W0[q], w2 = W1[q];
      const float g1r = w1.x * f1r - w1.y * f1i, g1i = w1.x * f1i + w1.y * f1r;
      const float g2r = w2.x * f2r - w2.y * f2i, g2i = w2.x * f2i + w2.y * f2r;
      SB[PADQ(q)] = make_float2(g1r - g2i, g1i + g2r);
      SB[PADQ(m)] = make_float2(g1r + g2i, g2r - g1i);
    }
  }
  __syncthreads();
  // inverse
  float2 u[16];
#pragma unroll
  for (int r = 0; r < 16; ++r) u[r] = SB[PADQ(tid + 512 * r)];
  __syncthreads();
  dft16<true, false>(u);
  phase1_store<true>(SB, u, tid);
  __syncthreads();
  phase2<true>(SB, tid);
  float* o0 = convT + ((size_t)b * 512 + d0) * 4096;
  float* o1 = convT + ((size_t)b * 512 + d1) * 4096;
  phase3_inv_store(SB, tid, o0, o1);
}

// ---------------- pos FFN layer 1: p1 = silu(pos @ w1^T + b1)  [4096,256] ---
__global__ __launch_bounds__(256) void k_posffn1(const float* __restrict__ pos,
                                                 const float* __restrict__ w1,
                                                 const float* __restrict__ b1,
                                                 float* __restrict__ p1) {
  __shared__ float sp[16 * 128];
  const int tid = threadIdx.x;
  const int m0 = blockIdx.x * 16;
  const float4* src = (const float4*)(pos + (size_t)m0 * 128);
  float4* dst = (float4*)sp;
  for (int i = tid; i < 512; i += 256) dst[i] = src[i];
  __syncthreads();
  const int n = tid;
  float acc[16];
  const float bias = b1[n];
#pragma unroll
  for (int m = 0; m < 16; ++m) acc[m] = bias;
  const float* w = w1 + (size_t)n * 128;
  for (int k = 0; k < 128; ++k) {
    const float wv = w[k];
#pragma unroll
    for (int m = 0; m < 16; ++m) acc[m] = fmaf(sp[m * 128 + k], wv, acc[m]);
  }
#pragma unroll
  for (int m = 0; m < 16; ++m) {
    const float v = acc[m];
    p1[(size_t)(m0 + m) * 256 + n] = v / (1.f + __expf(-v));
  }
}

// ---- pos FFN layer 2 + window, write transposed whT[d][t] = win[t]*h[t][d] -
__global__ __launch_bounds__(256) void k_posffn2(const float* __restrict__ p1,
                                                 const float* __restrict__ w2,
                                                 const float* __restrict__ b2,
                                                 const float* __restrict__ a,
                                                 float* __restrict__ whT) {
  __shared__ float sp[16 * 256];
  __shared__ float so[16 * 512];
  const int tid = threadIdx.x;
  const int t0 = blockIdx.x * 16;
  const float4* src = (const float4*)(p1 + (size_t)t0 * 256);
  float4* dst = (float4*)sp;
  for (int i = tid; i < 1024; i += 256) dst[i] = src[i];
  __syncthreads();
  for (int half = 0; half < 2; ++half) {
    const int d = tid + half * 256;
    float acc[16];
    const float bias = b2[d];
#pragma unroll
    for (int m = 0; m < 16; ++m) acc[m] = bias;
    const float* w = w2 + (size_t)d * 256;
    for (int k = 0; k < 256; ++k) {
      const float wv = w[k];
#pragma unroll
      for (int m = 0; m < 16; ++m) acc[m] = fmaf(sp[m * 256 + k], wv, acc[m]);
    }
#pragma unroll
    for (int m = 0; m < 16; ++m) so[m * 512 + d] = acc[m];
  }
  __syncthreads();
  const float expa = __expf(a[0]);
  for (int half = 0; half < 2; ++half) {
    const int d = tid + half * 256;
    float out[16];
#pragma unroll
    for (int m = 0; m < 16; ++m) {
      const float win = __expf(-(float)(t0 + m) * expa);
      out[m] = so[m * 512 + d] * win;
    }
    float4* o4 = (float4*)(whT + (size_t)d * 4096 + t0);
    o4[0] = make_float4(out[0], out[1], out[2], out[3]);
    o4[1] = make_float4(out[4], out[5], out[6], out[7]);
    o4[2] = make_float4(out[8], out[9], out[10], out[11]);
    o4[3] = make_float4(out[12], out[13], out[14], out[15]);
  }
}

// ---------------- LN(z) + transpose to lnzT[b][d][t] ------------------------
__global__ __launch_bounds__(256) void k_ln_tr_z(const float* __restrict__ z,
                                                 const float* __restrict__ g,
                                                 const float* __restrict__ be,
                                                 float* __restrict__ lnzT) {
  __shared__ float sd[16 * 516];
  __shared__ float smu[16], srs[16];
  const int tid = threadIdx.x;
  const int b = blockIdx.y;
  const int t0 = blockIdx.x * 16;
  for (int i = tid; i < 16 * 128; i += 256) {
    const int row = i >> 7, c4 = i & 127;
    const float4 v = *(const float4*)(z + ((size_t)b * 4096 + t0 + row) * 512 + c4 * 4);
    *(float4*)(&sd[row * 516 + c4 * 4]) = v;
  }
  __syncthreads();
  const int r = tid >> 4, s = tid & 15;
  float sum = 0.f, sq = 0.f;
#pragma unroll
  for (int i = 0; i < 8; ++i) {
    const int c4 = s + 16 * i;
    const float4 v = *(const float4*)(&sd[r * 516 + c4 * 4]);
    sum += v.x + v.y + v.z + v.w;
    sq += v.x * v.x + v.y * v.y + v.z * v.z + v.w * v.w;
  }
#pragma unroll
  for (int off = 1; off < 16; off <<= 1) {
    sum += __shfl_xor(sum, off);
    sq += __shfl_xor(sq, off);
  }
  if (s == 0) {
    const float mu = sum * (1.f / 512.f);
    const float var = sq * (1.f / 512.f) - mu * mu;
    smu[r] = mu;
    srs[r] = rsqrtf(var + 1e-5f);
  }
  __syncthreads();
  for (int pass = 0; pass < 8; ++pass) {
    const int d = pass * 64 + (tid >> 2);
    const int q = tid & 3;
    const float gg = g[d], bb = be[d];
    float4 o;
    o.x = (sd[(q * 4 + 0) * 516 + d] - smu[q * 4 + 0]) * srs[q * 4 + 0] * gg + bb;
    o.y = (sd[(q * 4 + 1) * 516 + d] - smu[q * 4 + 1]) * srs[q * 4 + 1] * gg + bb;
    o.z = (sd[(q * 4 + 2) * 516 + d] - smu[q * 4 + 2]) * srs[q * 4 + 2] * gg + bb;
    o.w = (sd[(q * 4 + 3) * 516 + d] - smu[q * 4 + 3]) * srs[q * 4 + 3] * gg + bb;
    *(float4*)(lnzT + ((size_t)b * 512 + d) * 4096 + t0 + q * 4) = o;
  }
}

// ------ fuse: cwhz = convT^T + z ; t1 = LN(cwhz) -> [b][t][d] rows ----------
__global__ __launch_bounds__(256) void k_fuse_t1(const float* __restrict__ convT,
                                                 const float* __restrict__ z,
                                                 const float* __restrict__ g,
                                                 const float* __restrict__ be,
                                                 float* __restrict__ t1) {
  __shared__ float sd[16 * 516];
  __shared__ float smu[16], srs[16];
  const int tid = threadIdx.x;
  const int b = blockIdx.y;
  const int t0 = blockIdx.x * 16;
  for (int pass = 0; pass < 8; ++pass) {
    const int d = pass * 64 + (tid >> 2);
    const int q = tid & 3;
    const float4 v = *(const float4*)(convT + ((size_t)b * 512 + d) * 4096 + t0 + q * 4);
    sd[(q * 4 + 0) * 516 + d] = v.x;
    sd[(q * 4 + 1) * 516 + d] = v.y;
    sd[(q * 4 + 2) * 516 + d] = v.z;
    sd[(q * 4 + 3) * 516 + d] = v.w;
  }
  __syncthreads();
  const int r = tid >> 4, s = tid & 15;
  const float* zr = z + ((size_t)b * 4096 + t0 + r) * 512;
  float sum = 0.f, sq = 0.f;
#pragma unroll
  for (int i = 0; i < 8; ++i) {
    const int c4 = s + 16 * i;
    const float4 zv = *(const float4*)(zr + c4 * 4);
    float* p = &sd[r * 516 + c4 * 4];
    const float v0 = p[0] + zv.x, v1 = p[1] + zv.y, v2 = p[2] + zv.z, v3 = p[3] + zv.w;
    p[0] = v0; p[1] = v1; p[2] = v2; p[3] = v3;
    sum += v0 + v1 + v2 + v3;
    sq += v0 * v0 + v1 * v1 + v2 * v2 + v3 * v3;
  }
#pragma unroll
  for (int off = 1; off < 16; off <<= 1) {
    sum += __shfl_xor(sum, off);
    sq += __shfl_xor(sq, off);
  }
  if (s == 0) {
    const float mu = sum * (1.f / 512.f);
    const float var = sq * (1.f / 512.f) - mu * mu;
    smu[r] = mu;
    srs[r] = rsqrtf(var + 1e-5f);
  }
  __syncthreads();
  for (int i = tid; i < 16 * 128; i += 256) {
    const int row = i >> 7, c4 = i & 127;
    const float mu = smu[row], rs = srs[row];
    const float4 gv = *(const float4*)(g + c4 * 4);
    const float4 bv = *(const float4*)(be + c4 * 4);
    const float* p = &sd[row * 516 + c4 * 4];
    float4 o;
    o.x = (p[0] - mu) * rs * gv.x + bv.x;
    o.y = (p[1] - mu) * rs * gv.y + bv.y;
    o.z = (p[2] - mu) * rs * gv.z + bv.z;
    o.w = (p[3] - mu) * rs * gv.w + bv.w;
    *(float4*)(t1 + ((size_t)b * 4096 + t0 + row) * 512 + c4 * 4) = o;
  }
}

// ---------------- f32 -> bf16 convert (grid-stride, float4-wise) ------------
__global__ __launch_bounds__(256) void k_cvt_bf16(const float* __restrict__ in,
                                                  unsigned short* __restrict__ out,
                                                  int n4) {
  const int stride = gridDim.x * 256;
  for (int i = blockIdx.x * 256 + threadIdx.x; i < n4; i += stride) {
    const float4 v = ((const float4*)in)[i];
    ushort4 o;
    o.x = to_bf16_bits(v.x);
    o.y = to_bf16_bits(v.y);
    o.z = to_bf16_bits(v.z);
    o.w = to_bf16_bits(v.w);
    ((ushort4*)out)[i] = o;
  }
}

// ---------------- LN(y) rows -> bf16 ----------------------------------------
__global__ __launch_bounds__(256) void k_lny(const float* __restrict__ y,
                                             const float* __restrict__ g,
                                             const float* __restrict__ be,
                                             unsigned short* __restrict__ out) {
  const int tid = threadIdx.x;
  const int lane = tid & 63, w = tid >> 6;
  const size_t row = (size_t)blockIdx.x * 4 + w;
  const float4* yr = (const float4*)(y + row * 512);
  const float4 v0 = yr[lane], v1 = yr[lane + 64];
  float sum = v0.x + v0.y + v0.z + v0.w + v1.x + v1.y + v1.z + v1.w;
  float sq = v0.x * v0.x + v0.y * v0.y + v0.z * v0.z + v0.w * v0.w +
             v1.x * v1.x + v1.y * v1.y + v1.z * v1.z + v1.w * v1.w;
#pragma unroll
  for (int off = 1; off < 64; off <<= 1) {
    sum += __shfl_xor(sum, off);
    sq += __shfl_xor(sq, off);
  }
  const float mu = sum * (1.f / 512.f);
  const float var = sq * (1.f / 512.f) - mu * mu;
  const float rs = rsqrtf(var + 1e-5f);
  const float4* g4 = (const float4*)g;
  const float4* b4 = (const float4*)be;
  const float4 g0 = g4[lane], g1 = g4[lane + 64];
  const float4 bb0 = b4[lane], bb1 = b4[lane + 64];
  ushort4 o0, o1;
  o0.x = to_bf16_bits((v0.x - mu) * rs * g0.x + bb0.x);
  o0.y = to_bf16_bits((v0.y - mu) * rs * g0.y + bb0.y);
  o0.z = to_bf16_bits((v0.z - mu) * rs * g0.z + bb0.z);
  o0.w = to_bf16_bits((v0.w - mu) * rs * g0.w + bb0.w);
  o1.x = to_bf16_bits((v1.x - mu) * rs * g1.x + bb1.x);
  o1.y = to_bf16_bits((v1.y - mu) * rs * g1.y + bb1.y);
  o1.z = to_bf16_bits((v1.z - mu) * rs * g1.z + bb1.z);
  o1.w = to_bf16_bits((v1.w - mu) * rs * g1.w + bb1.w);
  ((ushort4*)out)[row * 128 + lane] = o0;
  ((ushort4*)out)[row * 128 + lane + 64] = o1;
}

// ---------------- bf16 MFMA GEMM: C = A[M,K] @ B[N,K]^T + epi ---------------
// 1D grid, XCD-chunked swizzle (gridDim.x % 8 == 0). NXB = N/128 panels.
// EPI 0: silu(v+bias)->bf16  EPI 1: (v+bias)*extra->f32  EPI 2: (v+bias)+extra->f32
template <int EPI, int NXB>
__global__ __launch_bounds__(256) void k_gemm(const unsigned short* __restrict__ A,
                                              const unsigned short* __restrict__ Bw,
                                              const float* __restrict__ bias,
                                              const float* __restrict__ extra,
                                              void* __restrict__ Cout,
                                              int M, int N, int K) {
  __shared__ unsigned short sA[128 * 32];
  __shared__ unsigned short sB[128 * 32];
  const int tid = threadIdx.x;
  const int lane = tid & 63;
  const int w = tid >> 6;
  const int wr = w >> 1, wc = w & 1;
  // XCD chunk swizzle: consecutive logical tiles land on the same XCD
  const int cpx = gridDim.x >> 3;
  const int lid = (blockIdx.x & 7) * cpx + (blockIdx.x >> 3);
  const int n0 = (lid % NXB) * 128, m0 = (lid / NXB) * 128;
  f32x4 acc[4][4];
#pragma unroll
  for (int m = 0; m < 4; ++m)
#pragma unroll
    for (int n = 0; n < 4; ++n) acc[m][n] = (f32x4){0.f, 0.f, 0.f, 0.f};

  const int c_row = lane >> 2;
  const int c_off = (lane & 3) * 16;  // byte offset within 64B row
  const int nk = K >> 5;
  const int rA = lane & 15, kq = (lane >> 4) * 8;

  for (int kt = 0; kt < nk; ++kt) {
    __syncthreads();
    const int kb = kt * 32;
#pragma unroll
    for (int i = 0; i < 2; ++i) {
      const int ch = w * 2 + i;
      const int row = ch * 16 + c_row;
      gld_lds16((const char*)(A + (size_t)(m0 + row) * K + kb) + c_off,
                (char*)sA + ch * 1024);
      gld_lds16((const char*)(Bw + (size_t)(n0 + row) * K + kb) + c_off,
                (char*)sB + ch * 1024);
    }
    __syncthreads();
    bf16x8 af[4], bfv[4];
#pragma unroll
    for (int m = 0; m < 4; ++m)
      af[m] = *(const bf16x8*)(sA + (wr * 64 + m * 16 + rA) * 32 + kq);
#pragma unroll
    for (int n = 0; n < 4; ++n)
      bfv[n] = *(const bf16x8*)(sB + (wc * 64 + n * 16 + rA) * 32 + kq);
#pragma unroll
    for (int m = 0; m < 4; ++m)
#pragma unroll
      for (int n = 0; n < 4; ++n)
        acc[m][n] = __builtin_amdgcn_mfma_f32_16x16x32_bf16(af[m], bfv[n], acc[m][n], 0, 0, 0);
  }

  const int r0 = m0 + wr * 64 + (lane >> 4) * 4;
  const int c0 = n0 + wc * 64 + rA;
#pragma unroll
  for (int n = 0; n < 4; ++n) {
    const int cc = c0 + n * 16;
    const float bv = bias[cc];
#pragma unroll
    for (int m = 0; m < 4; ++m) {
#pragma unroll
      for (int j = 0; j < 4; ++j) {
        const int rr = r0 + m * 16 + j;
        const float v = acc[m][n][j] + bv;
        if constexpr (EPI == 0) {
          const float sv = v / (1.f + __expf(-v));
          ((unsigned short*)Cout)[(size_t)rr * N + cc] = to_bf16_bits(sv);
        } else if constexpr (EPI == 1) {
          ((float*)Cout)[(size_t)rr * N + cc] = v * extra[(size_t)rr * N + cc];
        } else {
          ((float*)Cout)[(size_t)rr * N + cc] = v + extra[(size_t)rr * N + cc];
        }
      }
    }
  }
}

// ---------------------------------------------------------------------------
extern "C" void kernel_launch(void* const* d_in, const int* in_sizes, int n_in,
                              void* d_out, int out_size, void* d_ws, size_t ws_size,
                              hipStream_t stream) {
  const float* z = (const float*)d_in[0];
  const float* x = (const float*)d_in[1];
  const float* pos = (const float*)d_in[2];
  const float* pos_w1 = (const float*)d_in[3];
  const float* pos_b1 = (const float*)d_in[4];
  const float* pos_w2 = (const float*)d_in[5];
  const float* pos_b2 = (const float*)d_in[6];
  const float* a = (const float*)d_in[7];
  const float* ffn_w1 = (const float*)d_in[8];
  const float* ffn_b1 = (const float*)d_in[9];
  const float* ffn_w2 = (const float*)d_in[10];
  const float* ffn_b2 = (const float*)d_in[11];
  const float* ffnx_w1 = (const float*)d_in[12];
  const float* ffnx_b1 = (const float*)d_in[13];
  const float* ffnx_w2 = (const float*)d_in[14];
  const float* ffnx_b2 = (const float*)d_in[15];
  const float* ln_g = (const float*)d_in[16];
  const float* ln_b = (const float*)d_in[17];
  float* outp = (float*)d_out;

  char* ws = (char*)d_ws;
  const size_t MiB = 1ull << 20;
  // phase-overlapped workspace (125 MiB total)
  float* p1 = (float*)(ws + 0);                               // 4 MiB (phase A)
  float* whT = (float*)(ws + 4 * MiB);                        // 8 MiB (phase A)
  unsigned short* wb_fx1 = (unsigned short*)(ws + 0);         // 1 MiB (after posffn2)
  unsigned short* wb_fx2 = (unsigned short*)(ws + 1 * MiB);
  unsigned short* wb_f1 = (unsigned short*)(ws + 2 * MiB);
  unsigned short* wb_f2 = (unsigned short*)(ws + 3 * MiB);
  float2* wfhT = (float2*)(ws + 12 * MiB);                    // 16.01 MiB
  unsigned short* xb = (unsigned short*)(ws + 12 * MiB);      // 16 MiB (after conv)
  float* lnzT = (float*)(ws + 29 * MiB);                      // 32 MiB
  float* yb = (float*)(ws + 29 * MiB);                        // 32 MiB (after conv)
  float* convT = (float*)(ws + 61 * MiB);                     // 32 MiB
  unsigned short* H = (unsigned short*)(ws + 61 * MiB);       // 32 MiB (after fuse)
  float* t1 = (float*)(ws + 93 * MiB);                        // 32 MiB
  unsigned short* ylnb = (unsigned short*)(ws + 93 * MiB);    // 16 MiB (after gemm2)

  // filter path
  k_posffn1<<<256, 256, 0, stream>>>(pos, pos_w1, pos_b1, p1);
  k_posffn2<<<256, 256, 0, stream>>>(p1, pos_w2, pos_b2, a, whT);
  k_filter_fft<<<256, 512, 0, stream>>>(whT, wfhT);
  // weight converts (p1 region now dead)
  k_cvt_bf16<<<256, 256, 0, stream>>>(ffnx_w1, wb_fx1, (1024 * 512) / 4);
  k_cvt_bf16<<<256, 256, 0, stream>>>(ffnx_w2, wb_fx2, (512 * 1024) / 4);
  k_cvt_bf16<<<256, 256, 0, stream>>>(ffn_w1, wb_f1, (1024 * 512) / 4);
  k_cvt_bf16<<<256, 256, 0, stream>>>(ffn_w2, wb_f2, (512 * 1024) / 4);
  // data path: LN+transpose -> FFT conv -> transpose back + LN
  k_ln_tr_z<<<dim3(256, 4), 256, 0, stream>>>(z, ln_g, ln_b, lnzT);
  k_conv_fft<<<dim3(256, 4), 512, 0, stream>>>(lnzT, wfhT, convT);
  k_fuse_t1<<<dim3(256, 4), 256, 0, stream>>>(convT, z, ln_g, ln_b, t1);
  // FFN chain (bf16 MFMA)
  k_cvt_bf16<<<4096, 256, 0, stream>>>(x, xb, (MSEQ * 512) / 4);
  k_gemm<0, 8><<<1024, 256, 0, stream>>>(xb, wb_fx1, ffnx_b1, nullptr, H, MSEQ, 1024, 512);
  k_gemm<1, 4><<<512, 256, 0, stream>>>(H, wb_fx2, ffnx_b2, t1, yb, MSEQ, 512, 1024);
  k_lny<<<4096, 256, 0, stream>>>(yb, ln_g, ln_b, ylnb);
  k_gemm<0, 8><<<1024, 256, 0, stream>>>(ylnb, wb_f1, ffn_b1, nullptr, H, MSEQ, 1024, 512);
  k_gemm<2, 4><<<512, 256, 0, stream>>>(H, wb_f2, ffn_b2, yb, outp, MSEQ, 512, 1024);
}